// Round 8
// baseline (302.303 us; speedup 1.0000x reference)
//
#include <hip/hip_runtime.h>
#include <hip/hip_bf16.h>
#include <math.h>

#define BN_C 0.9999950000375f
#define NB 16
#define NC 22
#define NT 16000
#define NPAIR 253
#define NSEQ 251
#define ND 48
#define TR 8
#define TE 18

__device__ __forceinline__ unsigned short f2bf(float f) {
    union { float f; unsigned int u; } v; v.f = f;
    unsigned int r = v.u + 0x7fff + ((v.u >> 16) & 1);
    return (unsigned short)(r >> 16);
}
__device__ __forceinline__ float bf2f(unsigned short s) {
    union { unsigned int u; float f; } v; v.u = ((unsigned int)s) << 16;
    return v.f;
}

// ---------------- y production ----------------
__global__ __launch_bounds__(256) void k_y(const float* __restrict__ x,
                                           const float* __restrict__ dw1,
                                           __hip_bfloat16* __restrict__ y) {
    int gid = blockIdx.x * 256 + threadIdx.x; // 128000
    int b = gid / 8000, tp = gid % 8000;
    int t = tp * 2;
    const float* xb = x + (size_t)b * NC * NT + t;
    float a0[32], a1[32];
    #pragma unroll
    for (int j = 0; j < 32; j++) { a0[j] = 0.f; a1[j] = 0.f; }
    for (int h = 0; h < NC; h++) {
        float2 xv = *(const float2*)&xb[(size_t)h * NT];
        #pragma unroll
        for (int j = 0; j < 32; j++) {
            float w = dw1[j * NC + h];
            a0[j] += w * xv.x; a1[j] += w * xv.y;
        }
    }
    unsigned int* yo = (unsigned int*)(y + (size_t)b * 32 * NT + t);
    #pragma unroll
    for (int j = 0; j < 32; j++) {
        unsigned int pk = (unsigned int)f2bf(a0[j]) | ((unsigned int)f2bf(a1[j]) << 16);
        yo[j * (NT / 2)] = pk;
    }
}

// ---------------- Riemannian branch ----------------
#define TCHUNK 500
#define XROW 504
__global__ __launch_bounds__(256) void k_covS(const float* __restrict__ x,
                                              float* __restrict__ covP,
                                              float* __restrict__ sumP) {
    int chunk = blockIdx.x, b = blockIdx.y;
    int t0 = chunk * TCHUNK;
    __shared__ unsigned short xs[NC * XROW];
    const float* xp = x + (size_t)b * NC * NT + t0;
    for (int i = threadIdx.x; i < NC * 126; i += 256) {
        int c = i / 126, q = i % 126;
        unsigned long long pk = 0ull;
        if (q < 125) {
            float4 v = *(const float4*)&xp[(size_t)c * NT + 4 * q];
            pk = (unsigned long long)f2bf(v.x) | ((unsigned long long)f2bf(v.y) << 16)
               | ((unsigned long long)f2bf(v.z) << 32) | ((unsigned long long)f2bf(v.w) << 48);
        }
        *(unsigned long long*)&xs[c * XROW + 4 * q] = pk;
    }
    __syncthreads();
    int p = threadIdx.x;
    if (p < NPAIR) {
        int c = 0, r = p;
        while (r >= NC - c) { r -= NC - c; c++; }
        int d = c + r;
        const unsigned short* xc = &xs[c * XROW];
        const unsigned short* xd = &xs[d * XROW];
        float a0 = 0, a1 = 0, a2 = 0, a3 = 0;
        float s0 = 0, s1 = 0, s2 = 0, s3 = 0;
        for (int t = 0; t < XROW; t += 8) {
            uint4 pc = *(const uint4*)&xc[t];
            uint4 pd = *(const uint4*)&xd[t];
            float c0 = bf2f((unsigned short)pc.x), c1 = bf2f((unsigned short)(pc.x >> 16));
            float c2 = bf2f((unsigned short)pc.y), c3 = bf2f((unsigned short)(pc.y >> 16));
            float c4 = bf2f((unsigned short)pc.z), c5 = bf2f((unsigned short)(pc.z >> 16));
            float c6 = bf2f((unsigned short)pc.w), c7 = bf2f((unsigned short)(pc.w >> 16));
            float d0 = bf2f((unsigned short)pd.x), d1 = bf2f((unsigned short)(pd.x >> 16));
            float d2 = bf2f((unsigned short)pd.y), d3 = bf2f((unsigned short)(pd.y >> 16));
            float d4 = bf2f((unsigned short)pd.z), d5 = bf2f((unsigned short)(pd.z >> 16));
            float d6 = bf2f((unsigned short)pd.w), d7 = bf2f((unsigned short)(pd.w >> 16));
            a0 += c0 * d0 + c4 * d4; a1 += c1 * d1 + c5 * d5;
            a2 += c2 * d2 + c6 * d6; a3 += c3 * d3 + c7 * d7;
            s0 += c0 + c4; s1 += c1 + c5; s2 += c2 + c6; s3 += c3 + c7;
        }
        covP[(size_t)chunk * NB * NPAIR + b * NPAIR + p] = (a0 + a1) + (a2 + a3);
        if (c == d) sumP[(size_t)chunk * NB * NC + b * NC + c] = (s0 + s1) + (s2 + s3);
    }
}

// partial-reduce + trace + register Cholesky + MLP, all in one: grid 16, block 256
__global__ __launch_bounds__(256) void k_cholfeat(
    const float* __restrict__ covP, const float* __restrict__ sumP,
    const float* __restrict__ w1, const float* __restrict__ b1,
    const float* __restrict__ w2, const float* __restrict__ b2,
    float* __restrict__ rfeat) {
    int b = blockIdx.x, t = threadIdx.x;
    __shared__ float ssA[NB][NC];
    __shared__ float covL[484];
    __shared__ float trS[NB];
    __shared__ float dvs[NC];
    __shared__ float hid[256];
    __shared__ float part[4][ND];
    if (t < NB) trS[t] = 0.f;
    // all-batch channel sums
    for (int i = t; i < NB * NC; i += 256) {
        int bb = i / NC, c = i % NC;
        float s = 0.f;
        for (int ch = 0; ch < 32; ch++) s += sumP[(size_t)ch * NB * NC + bb * NC + c];
        ssA[bb][c] = s;
    }
    __syncthreads();
    // own cov matrix
    if (t < NPAIR) {
        int c = 0, r = t;
        while (r >= NC - c) { r -= NC - c; c++; }
        int d = c + r;
        float v = 0.f;
        for (int ch = 0; ch < 32; ch++) v += covP[(size_t)ch * NB * NPAIR + b * NPAIR + t];
        v = (v - ssA[b][c] * ssA[b][d] / (float)NT) / (float)(NT - 1);
        if (c == d) v += 1e-5f;
        covL[c * NC + d] = v;
        covL[d * NC + c] = v;
    }
    // all-batch diagonals -> trace sums
    for (int i = t; i < NB * NC; i += 256) {
        int bb = i / NC, c = i % NC;
        int pos = c * NC - c * (c - 1) / 2; // pair index of (c,c)
        float v = 0.f;
        for (int ch = 0; ch < 32; ch++) v += covP[(size_t)ch * NB * NPAIR + bb * NPAIR + pos];
        v = (v - ssA[bb][c] * ssA[bb][c] / (float)NT) / (float)(NT - 1) + 1e-5f;
        atomicAdd(&trS[bb], v);
    }
    __syncthreads();
    float trs = 0.f;
    for (int i = 0; i < NB; i++) trs += trS[i];
    float trm = trs * (0.001f / (float)NB);
    // Cholesky in wave 0 registers
    if (t < 64) {
        int lane = t;
        float a[NC];
        #pragma unroll
        for (int j = 0; j < NC; j++) {
            float v = (lane < NC) ? covL[lane * NC + j] : 0.f;
            a[j] = v + ((j == lane) ? trm : 0.f);
        }
        float diagv = 1.f;
        #pragma unroll
        for (int k = 0; k < NC; k++) {
            float akk = __shfl(a[k], k);
            float dk = sqrtf(akk);
            if (lane == k) { a[k] = dk; diagv = dk; }
            else if (lane > k) a[k] /= dk;
            float myak = a[k];
            #pragma unroll
            for (int j = k + 1; j < NC; j++) {
                float ljk = __shfl(myak, j);
                if (lane >= j) a[j] -= myak * ljk;
            }
        }
        if (lane < NC) dvs[lane] = diagv * logf(fmaxf(diagv, 1e-10f));
    }
    __syncthreads();
    {
        float acc = b1[t];
        #pragma unroll
        for (int d = 0; d < NC; d++) {
            int pos = d * NC - d * (d - 1) / 2;
            acc += dvs[d] * w1[pos * 256 + t];
        }
        hid[t] = (acc > 0.f) ? acc : expm1f(acc);
    }
    __syncthreads();
    if (t < 192) {
        int col = t % ND, kc = t / ND;
        float a = 0.f;
        #pragma unroll
        for (int i = 0; i < 64; i++) a += hid[kc * 64 + i] * w2[(kc * 64 + i) * ND + col];
        part[kc][col] = a;
    }
    __syncthreads();
    if (t < ND)
        rfeat[b * ND + t] = b2[t] + part[0][t] + part[1][t] + part[2][t] + part[3][t];
}

// ---------------- Conv branch: 2 pooled outputs per thread ----------------
#define CT2 512
__global__ __launch_bounds__(256) void k_conv64(const __hip_bfloat16* __restrict__ y,
                                                const float* __restrict__ c1w,
                                                float* __restrict__ p) {
    int tile = blockIdx.x, j = blockIdx.y, b = blockIdx.z;
    int u0 = tile * CT2;
    __shared__ float yt[4680]; // 4160 values padded idx+(idx>>3)
    const __hip_bfloat16* yp = y + ((size_t)(b * 32 + j)) * NT;
    int tbase = u0 * 8 - 32;
    for (int q = threadIdx.x; q < 2080; q += 256) {
        int i = 2 * q;
        int tq = tbase + i;
        float v0 = 0.f, v1 = 0.f;
        if (tq >= 0 && tq + 1 < NT) {
            unsigned int pk = *(const unsigned int*)(yp + tq);
            v0 = bf2f((unsigned short)pk); v1 = bf2f((unsigned short)(pk >> 16));
        } else {
            if (tq >= 0 && tq < NT) v0 = __bfloat162float(yp[tq]);
            if (tq + 1 >= 0 && tq + 1 < NT) v1 = __bfloat162float(yp[tq + 1]);
        }
        yt[i + (i >> 3)] = v0;
        int i1 = i + 1;
        yt[i1 + (i1 >> 3)] = v1;
    }
    __syncthreads();
    const float* cf = c1w + (j >> 1) * 64; // wave-uniform -> scalar loads
    int u = u0 + 2 * threadIdx.x;
    if (u < 2000) {
        int off = 16 * threadIdx.x;
        float acc[16];
        #pragma unroll
        for (int s = 0; s < 16; s++) acc[s] = 0.f;
        #pragma unroll
        for (int kb = 0; kb < 64; kb += 16) {
            float Y[31];
            #pragma unroll
            for (int m = 0; m < 31; m++) {
                int idx = off + kb + m;
                Y[m] = yt[idx + (idx >> 3)];
            }
            #pragma unroll
            for (int k = 0; k < 16; k++) {
                float c = cf[kb + k];
                #pragma unroll
                for (int s = 0; s < 16; s++) acc[s] += c * Y[k + s];
            }
        }
        const float bn2 = BN_C * BN_C;
        float pv0 = 0.f, pv1 = 0.f;
        #pragma unroll
        for (int s = 0; s < 8; s++) {
            float z0 = bn2 * acc[s];
            pv0 += (z0 > 0.f) ? z0 : expm1f(z0);
            float z1 = bn2 * acc[8 + s];
            pv1 += (z1 > 0.f) ? z1 : expm1f(z1);
        }
        size_t base = ((size_t)(b * 32 + j)) * 2000;
        p[base + u] = pv0 * 0.125f;
        if (u + 1 < 2000) p[base + u + 1] = pv1 * 0.125f;
    }
}

// ---------------- stage2 + tc1/tc2 + fusion + pos_enc, fused ----------------
// grid dim3(63,16), block 256; 4 n per block with 6-wide feat halo window
__global__ __launch_bounds__(256) void k_stage2fuse(
    const float* __restrict__ p, const float* __restrict__ dw2,
    const float* __restrict__ pw, const float* __restrict__ rfeat,
    const float* __restrict__ tc1w, const float* __restrict__ tc1b,
    const float* __restrict__ tc2w, const float* __restrict__ tc2b,
    const float* __restrict__ fp, const float* __restrict__ pe,
    float* __restrict__ fused) {
    int bx = blockIdx.x, b = blockIdx.y, t = threadIdx.x;
    __shared__ float pt[32][64];    // 63 used
    __shared__ float dval[32][48];  // [j][w*8+s], w in 0..5
    __shared__ float feat6[6][ND];
    __shared__ float w2s[512];
    __shared__ float pws[1536];
    __shared__ float g1[4][24];
    __shared__ float row[4][ND];
    for (int i = t; i < 512; i += 256) w2s[i] = dw2[i];
    for (int i = t; i < 1536; i += 256) pws[i] = pw[i];
    int gt0 = 32 * bx - 24;
    for (int i = t; i < 32 * 63; i += 256) {
        int j = i / 63, tt = i % 63;
        int gt = gt0 + tt;
        pt[j][tt] = (gt >= 0 && gt < 2000) ? p[((size_t)(b * 32 + j)) * 2000 + gt] : 0.f;
    }
    __syncthreads();
    // dw2 conv: 32 j x 6 w x 8 s
    for (int i = t; i < 1536; i += 256) {
        int j = i / 48, su = i % 48;
        int w = su >> 3, s = su & 7;
        float a = 0.f;
        #pragma unroll
        for (int k = 0; k < 16; k++) a += w2s[j * 16 + k] * pt[j][8 * w + s + k];
        dval[j][su] = a * BN_C;
    }
    __syncthreads();
    // pw + elu + pool8 -> feat6
    for (int i = t; i < 6 * ND; i += 256) {
        int w = i / ND, col = i % ND;
        int u2 = 4 * bx - 2 + w;
        float acc = 0.f;
        if (u2 >= 0 && u2 < 250) {
            float wreg[32];
            #pragma unroll
            for (int j = 0; j < 32; j++) wreg[j] = pws[col * 32 + j];
            #pragma unroll
            for (int s = 0; s < 8; s++) {
                float e = 0.f;
                #pragma unroll
                for (int j = 0; j < 32; j++) e += wreg[j] * dval[j][w * 8 + s];
                e *= BN_C;
                acc += (e > 0.f) ? e : expm1f(e);
            }
            acc *= 0.125f;
        }
        feat6[w][col] = acc;
    }
    __syncthreads();
    // tc1 + gelu
    if (t < 96) {
        int sub = t / 24, m = t % 24;
        int n = 4 * bx + sub;
        if (n >= 1 && n < NSEQ) {
            float a = tc1b[m];
            #pragma unroll
            for (int k = 0; k < 3; k++) {
                int w = sub + k; // feat6 index of u-1+k
                a += tc1w[m * 6 + k] * feat6[w][2 * m]
                   + tc1w[m * 6 + 3 + k] * feat6[w][2 * m + 1];
            }
            float z = a * BN_C;
            g1[sub][m] = 0.5f * z * (1.f + erff(z * 0.70710678f));
        }
    }
    __syncthreads();
    // tc2 + residual (or rfeat for n=0)
    if (t < 192) {
        int sub = t / ND, col = t % ND;
        int n = 4 * bx + sub;
        if (n < NSEQ) {
            if (n == 0) {
                row[sub][col] = rfeat[b * ND + col];
            } else {
                float a = tc2b[col];
                #pragma unroll
                for (int m = 0; m < 24; m++) a += tc2w[col * 24 + m] * g1[sub][m];
                row[sub][col] = feat6[sub + 1][col] + a;
            }
        }
    }
    __syncthreads();
    // fusion matmul + pos_enc
    if (t < 192) {
        int sub = t / ND, col = t % ND;
        int n = 4 * bx + sub;
        if (n < NSEQ) {
            float o = pe[n * ND + col];
            for (int c = 0; c < ND; c++) o += row[sub][c] * fp[c * ND + col];
            fused[((size_t)b * NSEQ + n) * ND + col] = o;
        }
    }
}

// ---------------- Fused transformer layer: block 512 ----------------
__global__ __launch_bounds__(512) void k_layer(
    float* __restrict__ fused,
    const float* __restrict__ g1v, const float* __restrict__ b1v,
    const float* __restrict__ qw, const float* __restrict__ qb,
    const float* __restrict__ apw, const float* __restrict__ apb,
    const float* __restrict__ g2v, const float* __restrict__ b2v,
    const float* __restrict__ w1, const float* __restrict__ fb1,
    const float* __restrict__ w2, const float* __restrict__ fb2) {
    int tile = blockIdx.x, b = blockIdx.y;
    int n0 = tile * TR;
    int t = threadIdx.x;
    __shared__ float row[TE][ND];
    __shared__ float hh[TE][ND];
    __shared__ float qkvS[TE * 144];
    __shared__ float ob[TR][ND];
    __shared__ float nrow[TR][ND];
    __shared__ float mrs[TE][2];
    __shared__ float part[4][TR][ND];
    float* hid = qkvS;

    for (int i = t; i < TE * ND; i += 512) {
        int e = i / ND, c = i % ND;
        int n = n0 - 5 + e;
        row[e][c] = (n >= 0 && n < NSEQ) ? fused[((size_t)b * NSEQ + n) * ND + c] : 0.f;
    }
    __syncthreads();
    if (t < TE * 16) {
        int r = t >> 4, i = t & 15;
        float v0 = row[r][i], v1 = row[r][i + 16], v2 = row[r][i + 32];
        float s = v0 + v1 + v2;
        s += __shfl_down(s, 8, 16); s += __shfl_down(s, 4, 16);
        s += __shfl_down(s, 2, 16); s += __shfl_down(s, 1, 16);
        float m = __shfl(s, 0, 16) * (1.f / ND);
        float d0 = v0 - m, d1 = v1 - m, d2 = v2 - m;
        float q = d0 * d0 + d1 * d1 + d2 * d2;
        q += __shfl_down(q, 8, 16); q += __shfl_down(q, 4, 16);
        q += __shfl_down(q, 2, 16); q += __shfl_down(q, 1, 16);
        if (i == 0) { mrs[r][0] = m; mrs[r][1] = rsqrtf(q * (1.f / ND) + 1e-5f); }
    }
    __syncthreads();
    for (int i = t; i < TE * ND; i += 512) {
        int e = i / ND, c = i % ND;
        hh[e][c] = (row[e][c] - mrs[e][0]) * mrs[e][1] * g1v[c] + b1v[c];
    }
    __syncthreads();
    if (t < 288) {
        int col = t % 144, eg = t / 144;
        float w[ND];
        #pragma unroll
        for (int c = 0; c < ND; c++) w[c] = qw[c * 144 + col];
        float bias = qb[col];
        for (int e = eg * 9; e < eg * 9 + 9; e++) {
            float a = bias;
            #pragma unroll
            for (int c = 0; c < ND; c++) a += hh[e][c] * w[c];
            qkvS[e * 144 + col] = a;
        }
    }
    __syncthreads();
    if (t < TR * 8) {
        int r = t >> 3, h = t & 7;
        int n = n0 + r;
        if (n < NSEQ) {
            int k0 = n - 5; if (k0 < 0) k0 = 0;
            int k1 = n + 5; if (k1 > NSEQ - 1) k1 = NSEQ - 1;
            int nk = k1 - k0 + 1;
            float q[6];
            #pragma unroll
            for (int d = 0; d < 6; d++) q[d] = qkvS[(r + 5) * 144 + h * 6 + d];
            float sc[11];
            float mx = -1e30f;
            for (int ki = 0; ki < nk; ki++) {
                int e = k0 + ki - n0 + 5;
                float s = 0;
                #pragma unroll
                for (int d = 0; d < 6; d++) s += q[d] * qkvS[e * 144 + 48 + h * 6 + d];
                s *= 0.4082482904638631f;
                sc[ki] = s; mx = fmaxf(mx, s);
            }
            float sum = 0;
            for (int ki = 0; ki < nk; ki++) { float e = expf(sc[ki] - mx); sc[ki] = e; sum += e; }
            float inv = 1.f / sum;
            float o[6] = {0, 0, 0, 0, 0, 0};
            for (int ki = 0; ki < nk; ki++) {
                int e = k0 + ki - n0 + 5;
                float pv = sc[ki] * inv;
                #pragma unroll
                for (int d = 0; d < 6; d++) o[d] += pv * qkvS[e * 144 + 96 + h * 6 + d];
            }
            #pragma unroll
            for (int d = 0; d < 6; d++) ob[r][h * 6 + d] = o[d];
        } else {
            #pragma unroll
            for (int d = 0; d < 6; d++) ob[r][h * 6 + d] = 0.f;
        }
    }
    __syncthreads();
    if (t < TR * ND) {
        int r = t / ND, col = t % ND;
        float a = apb[col];
        #pragma unroll
        for (int c = 0; c < ND; c++) a += ob[r][c] * apw[c * ND + col];
        nrow[r][col] = row[r + 5][col] + a;
    }
    __syncthreads();
    if (t < TR * 16) {
        int r = t >> 4, i = t & 15;
        float v0 = nrow[r][i], v1 = nrow[r][i + 16], v2 = nrow[r][i + 32];
        float s = v0 + v1 + v2;
        s += __shfl_down(s, 8, 16); s += __shfl_down(s, 4, 16);
        s += __shfl_down(s, 2, 16); s += __shfl_down(s, 1, 16);
        float m = __shfl(s, 0, 16) * (1.f / ND);
        float d0 = v0 - m, d1 = v1 - m, d2 = v2 - m;
        float q = d0 * d0 + d1 * d1 + d2 * d2;
        q += __shfl_down(q, 8, 16); q += __shfl_down(q, 4, 16);
        q += __shfl_down(q, 2, 16); q += __shfl_down(q, 1, 16);
        if (i == 0) { mrs[r][0] = m; mrs[r][1] = rsqrtf(q * (1.f / ND) + 1e-5f); }
    }
    __syncthreads();
    if (t < TR * ND) {
        int r = t / ND, c = t % ND;
        hh[r][c] = (nrow[r][c] - mrs[r][0]) * mrs[r][1] * g2v[c] + b2v[c];
    }
    __syncthreads();
    if (t < 384) {
        int col = t % 192, rg = t / 192;
        float w[ND];
        #pragma unroll
        for (int c = 0; c < ND; c++) w[c] = w1[c * 192 + col];
        float bias = fb1[col];
        for (int r = rg * 4; r < rg * 4 + 4; r++) {
            float a = bias;
            #pragma unroll
            for (int c = 0; c < ND; c++) a += hh[r][c] * w[c];
            hid[r * 192 + col] = 0.5f * a * (1.f + erff(a * 0.70710678f));
        }
    }
    __syncthreads();
    if (t < 384) {
        int col = t % ND, kc = (t / ND) & 3, rh = t / 192;
        float w[ND];
        #pragma unroll
        for (int i2 = 0; i2 < ND; i2++) w[i2] = w2[(kc * ND + i2) * ND + col];
        for (int r = rh * 4; r < rh * 4 + 4; r++) {
            float a = 0;
            #pragma unroll
            for (int i2 = 0; i2 < ND; i2++) a += hid[r * 192 + kc * ND + i2] * w[i2];
            part[kc][r][col] = a;
        }
    }
    __syncthreads();
    for (int i = t; i < TR * ND; i += 512) {
        int r = i / ND, c = i % ND;
        int n = n0 + r;
        if (n < NSEQ) {
            fused[((size_t)b * NSEQ + n) * ND + c] =
                nrow[r][c] + fb2[c] + part[0][r][c] + part[1][r][c] + part[2][r][c] + part[3][r][c];
        }
    }
}

__global__ void k_head(const float* __restrict__ fused, const float* __restrict__ lg,
                       const float* __restrict__ lb, const float* __restrict__ cw,
                       const float* __restrict__ cb, float* __restrict__ out) {
    int b = blockIdx.x, t = threadIdx.x;
    __shared__ float part[4][ND];
    __shared__ float gg[ND], mv[2];
    if (t < 192) {
        int col = t % ND, qt = t / ND;
        int nA = qt * 63;
        int nB = (nA + 63 < NSEQ) ? nA + 63 : NSEQ;
        float s = 0.f;
        for (int n = nA; n < nB; n++) s += fused[((size_t)b * NSEQ + n) * ND + col];
        part[qt][col] = s;
    }
    __syncthreads();
    if (t < ND) gg[t] = (part[0][t] + part[1][t] + part[2][t] + part[3][t]) * (1.f / NSEQ);
    __syncthreads();
    if (t == 0) {
        float m = 0;
        for (int c = 0; c < ND; c++) m += gg[c];
        m /= (float)ND;
        float v = 0;
        for (int c = 0; c < ND; c++) { float dd = gg[c] - m; v += dd * dd; }
        v /= (float)ND;
        mv[0] = m; mv[1] = rsqrtf(v + 1e-5f);
    }
    __syncthreads();
    if (t < ND) gg[t] = (gg[t] - mv[0]) * mv[1] * lg[t] + lb[t];
    __syncthreads();
    if (t < 4) {
        float a = cb[t];
        for (int c = 0; c < ND; c++) a += gg[c] * cw[c * 4 + t];
        out[b * 4 + t] = a;
    }
}

extern "C" void kernel_launch(void* const* d_in, const int* in_sizes, int n_in,
                              void* d_out, int out_size, void* d_ws, size_t ws_size,
                              hipStream_t stream) {
    const float* x       = (const float*)d_in[0];
    const float* riem_w1 = (const float*)d_in[1];
    const float* riem_b1 = (const float*)d_in[2];
    const float* riem_w2 = (const float*)d_in[3];
    const float* riem_b2 = (const float*)d_in[4];
    const float* conv1_w = (const float*)d_in[5];
    const float* dw1_w   = (const float*)d_in[6];
    const float* dw2_w   = (const float*)d_in[7];
    const float* pw_w    = (const float*)d_in[8];
    const float* tc1_w   = (const float*)d_in[9];
    const float* tc1_b   = (const float*)d_in[10];
    const float* tc2_w   = (const float*)d_in[11];
    const float* tc2_b   = (const float*)d_in[12];
    const float* fusion  = (const float*)d_in[13];
    const float* pos_enc = (const float*)d_in[14];
    const float* ln1_g   = (const float*)d_in[15];
    const float* ln1_b   = (const float*)d_in[16];
    const float* qkv_w   = (const float*)d_in[17];
    const float* qkv_b   = (const float*)d_in[18];
    const float* apw     = (const float*)d_in[19];
    const float* apb     = (const float*)d_in[20];
    const float* ln2_g   = (const float*)d_in[21];
    const float* ln2_b   = (const float*)d_in[22];
    const float* ffn_w1  = (const float*)d_in[23];
    const float* ffn_b1  = (const float*)d_in[24];
    const float* ffn_w2  = (const float*)d_in[25];
    const float* ffn_b2  = (const float*)d_in[26];
    const float* cls_g   = (const float*)d_in[27];
    const float* cls_b_  = (const float*)d_in[28];
    const float* cls_w   = (const float*)d_in[29];
    const float* cls_bb  = (const float*)d_in[30];
    float* out = (float*)d_out;

    float* ws = (float*)d_ws;
    float* covP  = ws;                 // 129536
    float* sumP  = ws + 129536;        // 11264
    float* rfeat = ws + 140800;        // 768
    float* fused = ws + 141568;        // 192768
    float* pbuf  = ws + 334336;        // 1024000
    __hip_bfloat16* ybuf = (__hip_bfloat16*)(ws + 1358336); // 8192000 bf16

    k_y<<<500, 256, 0, stream>>>(x, dw1_w, ybuf);
    k_covS<<<dim3(32, NB), 256, 0, stream>>>(x, covP, sumP);
    k_cholfeat<<<NB, 256, 0, stream>>>(covP, sumP, riem_w1, riem_b1, riem_w2, riem_b2, rfeat);

    k_conv64<<<dim3(4, 32, NB), 256, 0, stream>>>(ybuf, conv1_w, pbuf);
    k_stage2fuse<<<dim3(63, NB), 256, 0, stream>>>(pbuf, dw2_w, pw_w, rfeat,
                                                   tc1_w, tc1_b, tc2_w, tc2_b,
                                                   fusion, pos_enc, fused);

    for (int i = 0; i < 4; i++) {
        k_layer<<<dim3(32, NB), 512, 0, stream>>>(
            fused, ln1_g + i * 48, ln1_b + i * 48, qkv_w + i * 6912, qkv_b + i * 144,
            apw + i * 2304, apb + i * 48, ln2_g + i * 48, ln2_b + i * 48,
            ffn_w1 + i * 9216, ffn_b1 + i * 192, ffn_w2 + i * 9216, ffn_b2 + i * 48);
    }

    k_head<<<NB, 256, 0, stream>>>(fused, cls_g, cls_b_, cls_w, cls_bb, out);
}

// Round 9
// 298.565 us; speedup vs baseline: 1.0125x; 1.0125x over previous
//
#include <hip/hip_runtime.h>
#include <hip/hip_bf16.h>
#include <math.h>

#define BN_C 0.9999950000375f
#define NB 16
#define NC 22
#define NT 16000
#define NPAIR 253
#define NSEQ 251
#define ND 48
#define TR 8
#define TE 18

__device__ __forceinline__ unsigned short f2bf(float f) {
    union { float f; unsigned int u; } v; v.f = f;
    unsigned int r = v.u + 0x7fff + ((v.u >> 16) & 1);
    return (unsigned short)(r >> 16);
}
__device__ __forceinline__ float bf2f(unsigned short s) {
    union { unsigned int u; float f; } v; v.u = ((unsigned int)s) << 16;
    return v.f;
}

// ---------------- y production ----------------
__global__ __launch_bounds__(256) void k_y(const float* __restrict__ x,
                                           const float* __restrict__ dw1,
                                           __hip_bfloat16* __restrict__ y) {
    int gid = blockIdx.x * 256 + threadIdx.x; // 128000
    int b = gid / 8000, tp = gid % 8000;
    int t = tp * 2;
    const float* xb = x + (size_t)b * NC * NT + t;
    float a0[32], a1[32];
    #pragma unroll
    for (int j = 0; j < 32; j++) { a0[j] = 0.f; a1[j] = 0.f; }
    for (int h = 0; h < NC; h++) {
        float2 xv = *(const float2*)&xb[(size_t)h * NT];
        #pragma unroll
        for (int j = 0; j < 32; j++) {
            float w = dw1[j * NC + h];
            a0[j] += w * xv.x; a1[j] += w * xv.y;
        }
    }
    unsigned int* yo = (unsigned int*)(y + (size_t)b * 32 * NT + t);
    #pragma unroll
    for (int j = 0; j < 32; j++) {
        unsigned int pk = (unsigned int)f2bf(a0[j]) | ((unsigned int)f2bf(a1[j]) << 16);
        yo[j * (NT / 2)] = pk;
    }
}

// ---------------- Riemannian branch ----------------
// cov sums via atomics into dense covS/sums (must be zeroed): grid dim3(32,16), block 256
#define TCHUNK 500
#define XROW 504
__global__ __launch_bounds__(256) void k_covS(const float* __restrict__ x,
                                              float* __restrict__ covS,
                                              float* __restrict__ sums) {
    int chunk = blockIdx.x, b = blockIdx.y;
    int t0 = chunk * TCHUNK;
    __shared__ unsigned short xs[NC * XROW];
    const float* xp = x + (size_t)b * NC * NT + t0;
    for (int i = threadIdx.x; i < NC * 126; i += 256) {
        int c = i / 126, q = i % 126;
        unsigned long long pk = 0ull;
        if (q < 125) {
            float4 v = *(const float4*)&xp[(size_t)c * NT + 4 * q];
            pk = (unsigned long long)f2bf(v.x) | ((unsigned long long)f2bf(v.y) << 16)
               | ((unsigned long long)f2bf(v.z) << 32) | ((unsigned long long)f2bf(v.w) << 48);
        }
        *(unsigned long long*)&xs[c * XROW + 4 * q] = pk;
    }
    __syncthreads();
    int p = threadIdx.x;
    if (p < NPAIR) {
        int c = 0, r = p;
        while (r >= NC - c) { r -= NC - c; c++; }
        int d = c + r;
        const unsigned short* xc = &xs[c * XROW];
        const unsigned short* xd = &xs[d * XROW];
        float a0 = 0, a1 = 0, a2 = 0, a3 = 0;
        float s0 = 0, s1 = 0, s2 = 0, s3 = 0;
        for (int t = 0; t < XROW; t += 8) {
            uint4 pc = *(const uint4*)&xc[t];
            uint4 pd = *(const uint4*)&xd[t];
            float c0 = bf2f((unsigned short)pc.x), c1 = bf2f((unsigned short)(pc.x >> 16));
            float c2 = bf2f((unsigned short)pc.y), c3 = bf2f((unsigned short)(pc.y >> 16));
            float c4 = bf2f((unsigned short)pc.z), c5 = bf2f((unsigned short)(pc.z >> 16));
            float c6 = bf2f((unsigned short)pc.w), c7 = bf2f((unsigned short)(pc.w >> 16));
            float d0 = bf2f((unsigned short)pd.x), d1 = bf2f((unsigned short)(pd.x >> 16));
            float d2 = bf2f((unsigned short)pd.y), d3 = bf2f((unsigned short)(pd.y >> 16));
            float d4 = bf2f((unsigned short)pd.z), d5 = bf2f((unsigned short)(pd.z >> 16));
            float d6 = bf2f((unsigned short)pd.w), d7 = bf2f((unsigned short)(pd.w >> 16));
            a0 += c0 * d0 + c4 * d4; a1 += c1 * d1 + c5 * d5;
            a2 += c2 * d2 + c6 * d6; a3 += c3 * d3 + c7 * d7;
            s0 += c0 + c4; s1 += c1 + c5; s2 += c2 + c6; s3 += c3 + c7;
        }
        atomicAdd(&covS[b * NPAIR + p], (a0 + a1) + (a2 + a3));
        if (c == d) atomicAdd(&sums[b * NC + c], (s0 + s1) + (s2 + s3));
    }
}

// dense covS -> cov(LDS) + trace + register Cholesky + MLP: grid 16, block 256
__global__ __launch_bounds__(256) void k_cholfeat(
    const float* __restrict__ covS, const float* __restrict__ sums,
    const float* __restrict__ w1, const float* __restrict__ b1,
    const float* __restrict__ w2, const float* __restrict__ b2,
    float* __restrict__ rfeat) {
    int b = blockIdx.x, t = threadIdx.x;
    __shared__ float covL[484];
    __shared__ float trS[NB];
    __shared__ float dvs[NC];
    __shared__ float hid[256];
    __shared__ float part[4][ND];
    if (t < NB) trS[t] = 0.f;
    __syncthreads();
    // own cov matrix (dense reads, L2-hot)
    if (t < NPAIR) {
        int c = 0, r = t;
        while (r >= NC - c) { r -= NC - c; c++; }
        int d = c + r;
        float v = (covS[b * NPAIR + t] - sums[b * NC + c] * sums[b * NC + d] / (float)NT)
                  / (float)(NT - 1);
        if (c == d) v += 1e-5f;
        covL[c * NC + d] = v;
        covL[d * NC + c] = v;
    }
    // all-batch diagonal -> trace sums (352 dense loads)
    for (int i = t; i < NB * NC; i += 256) {
        int bb = i / NC, c = i % NC;
        int pos = c * NC - c * (c - 1) / 2; // pair index of (c,c)
        float sc = sums[bb * NC + c];
        float v = (covS[bb * NPAIR + pos] - sc * sc / (float)NT) / (float)(NT - 1) + 1e-5f;
        atomicAdd(&trS[bb], v);
    }
    __syncthreads();
    float trs = 0.f;
    for (int i = 0; i < NB; i++) trs += trS[i];
    float trm = trs * (0.001f / (float)NB);
    // Cholesky in wave 0 registers
    if (t < 64) {
        int lane = t;
        float a[NC];
        #pragma unroll
        for (int j = 0; j < NC; j++) {
            float v = (lane < NC) ? covL[lane * NC + j] : 0.f;
            a[j] = v + ((j == lane) ? trm : 0.f);
        }
        float diagv = 1.f;
        #pragma unroll
        for (int k = 0; k < NC; k++) {
            float akk = __shfl(a[k], k);
            float dk = sqrtf(akk);
            if (lane == k) { a[k] = dk; diagv = dk; }
            else if (lane > k) a[k] /= dk;
            float myak = a[k];
            #pragma unroll
            for (int j = k + 1; j < NC; j++) {
                float ljk = __shfl(myak, j);
                if (lane >= j) a[j] -= myak * ljk;
            }
        }
        if (lane < NC) dvs[lane] = diagv * logf(fmaxf(diagv, 1e-10f));
    }
    __syncthreads();
    {
        float acc = b1[t];
        #pragma unroll
        for (int d = 0; d < NC; d++) {
            int pos = d * NC - d * (d - 1) / 2;
            acc += dvs[d] * w1[pos * 256 + t];
        }
        hid[t] = (acc > 0.f) ? acc : expm1f(acc);
    }
    __syncthreads();
    if (t < 192) {
        int col = t % ND, kc = t / ND;
        float a = 0.f;
        #pragma unroll
        for (int i = 0; i < 64; i++) a += hid[kc * 64 + i] * w2[(kc * 64 + i) * ND + col];
        part[kc][col] = a;
    }
    __syncthreads();
    if (t < ND)
        rfeat[b * ND + t] = b2[t] + part[0][t] + part[1][t] + part[2][t] + part[3][t];
}

// ---------------- Conv branch: 2 pooled outputs per thread ----------------
#define CT2 512
__global__ __launch_bounds__(256) void k_conv64(const __hip_bfloat16* __restrict__ y,
                                                const float* __restrict__ c1w,
                                                float* __restrict__ p) {
    int tile = blockIdx.x, j = blockIdx.y, b = blockIdx.z;
    int u0 = tile * CT2;
    __shared__ float yt[4680];
    const __hip_bfloat16* yp = y + ((size_t)(b * 32 + j)) * NT;
    int tbase = u0 * 8 - 32;
    for (int q = threadIdx.x; q < 2080; q += 256) {
        int i = 2 * q;
        int tq = tbase + i;
        float v0 = 0.f, v1 = 0.f;
        if (tq >= 0 && tq + 1 < NT) {
            unsigned int pk = *(const unsigned int*)(yp + tq);
            v0 = bf2f((unsigned short)pk); v1 = bf2f((unsigned short)(pk >> 16));
        } else {
            if (tq >= 0 && tq < NT) v0 = __bfloat162float(yp[tq]);
            if (tq + 1 >= 0 && tq + 1 < NT) v1 = __bfloat162float(yp[tq + 1]);
        }
        yt[i + (i >> 3)] = v0;
        int i1 = i + 1;
        yt[i1 + (i1 >> 3)] = v1;
    }
    __syncthreads();
    const float* cf = c1w + (j >> 1) * 64;
    int u = u0 + 2 * threadIdx.x;
    if (u < 2000) {
        int off = 16 * threadIdx.x;
        float acc[16];
        #pragma unroll
        for (int s = 0; s < 16; s++) acc[s] = 0.f;
        #pragma unroll
        for (int kb = 0; kb < 64; kb += 16) {
            float Y[31];
            #pragma unroll
            for (int m = 0; m < 31; m++) {
                int idx = off + kb + m;
                Y[m] = yt[idx + (idx >> 3)];
            }
            #pragma unroll
            for (int k = 0; k < 16; k++) {
                float c = cf[kb + k];
                #pragma unroll
                for (int s = 0; s < 16; s++) acc[s] += c * Y[k + s];
            }
        }
        const float bn2 = BN_C * BN_C;
        float pv0 = 0.f, pv1 = 0.f;
        #pragma unroll
        for (int s = 0; s < 8; s++) {
            float z0 = bn2 * acc[s];
            pv0 += (z0 > 0.f) ? z0 : expm1f(z0);
            float z1 = bn2 * acc[8 + s];
            pv1 += (z1 > 0.f) ? z1 : expm1f(z1);
        }
        size_t base = ((size_t)(b * 32 + j)) * 2000;
        p[base + u] = pv0 * 0.125f;
        if (u + 1 < 2000) p[base + u + 1] = pv1 * 0.125f;
    }
}

// ---------------- stage2 + tc1/tc2 + fusion + pos_enc, fused ----------------
__global__ __launch_bounds__(256) void k_stage2fuse(
    const float* __restrict__ p, const float* __restrict__ dw2,
    const float* __restrict__ pw, const float* __restrict__ rfeat,
    const float* __restrict__ tc1w, const float* __restrict__ tc1b,
    const float* __restrict__ tc2w, const float* __restrict__ tc2b,
    const float* __restrict__ fp, const float* __restrict__ pe,
    float* __restrict__ fused) {
    int bx = blockIdx.x, b = blockIdx.y, t = threadIdx.x;
    __shared__ float pt[32][64];
    __shared__ float dval[32][48];
    __shared__ float feat6[6][ND];
    __shared__ float w2s[512];
    __shared__ float pws[1536];
    __shared__ float g1[4][24];
    __shared__ float row[4][ND];
    for (int i = t; i < 512; i += 256) w2s[i] = dw2[i];
    for (int i = t; i < 1536; i += 256) pws[i] = pw[i];
    int gt0 = 32 * bx - 24;
    for (int i = t; i < 32 * 63; i += 256) {
        int j = i / 63, tt = i % 63;
        int gt = gt0 + tt;
        pt[j][tt] = (gt >= 0 && gt < 2000) ? p[((size_t)(b * 32 + j)) * 2000 + gt] : 0.f;
    }
    __syncthreads();
    for (int i = t; i < 1536; i += 256) {
        int j = i / 48, su = i % 48;
        int w = su >> 3, s = su & 7;
        float a = 0.f;
        #pragma unroll
        for (int k = 0; k < 16; k++) a += w2s[j * 16 + k] * pt[j][8 * w + s + k];
        dval[j][su] = a * BN_C;
    }
    __syncthreads();
    for (int i = t; i < 6 * ND; i += 256) {
        int w = i / ND, col = i % ND;
        int u2 = 4 * bx - 2 + w;
        float acc = 0.f;
        if (u2 >= 0 && u2 < 250) {
            float wreg[32];
            #pragma unroll
            for (int j = 0; j < 32; j++) wreg[j] = pws[col * 32 + j];
            #pragma unroll
            for (int s = 0; s < 8; s++) {
                float e = 0.f;
                #pragma unroll
                for (int j = 0; j < 32; j++) e += wreg[j] * dval[j][w * 8 + s];
                e *= BN_C;
                acc += (e > 0.f) ? e : expm1f(e);
            }
            acc *= 0.125f;
        }
        feat6[w][col] = acc;
    }
    __syncthreads();
    if (t < 96) {
        int sub = t / 24, m = t % 24;
        int n = 4 * bx + sub;
        if (n >= 1 && n < NSEQ) {
            float a = tc1b[m];
            #pragma unroll
            for (int k = 0; k < 3; k++) {
                int w = sub + k;
                a += tc1w[m * 6 + k] * feat6[w][2 * m]
                   + tc1w[m * 6 + 3 + k] * feat6[w][2 * m + 1];
            }
            float z = a * BN_C;
            g1[sub][m] = 0.5f * z * (1.f + erff(z * 0.70710678f));
        }
    }
    __syncthreads();
    if (t < 192) {
        int sub = t / ND, col = t % ND;
        int n = 4 * bx + sub;
        if (n < NSEQ) {
            if (n == 0) {
                row[sub][col] = rfeat[b * ND + col];
            } else {
                float a = tc2b[col];
                #pragma unroll
                for (int m = 0; m < 24; m++) a += tc2w[col * 24 + m] * g1[sub][m];
                row[sub][col] = feat6[sub + 1][col] + a;
            }
        }
    }
    __syncthreads();
    if (t < 192) {
        int sub = t / ND, col = t % ND;
        int n = 4 * bx + sub;
        if (n < NSEQ) {
            float o = pe[n * ND + col];
            for (int c = 0; c < ND; c++) o += row[sub][c] * fp[c * ND + col];
            fused[((size_t)b * NSEQ + n) * ND + col] = o;
        }
    }
}

// ---------------- Fused transformer layer: block 512 ----------------
__global__ __launch_bounds__(512) void k_layer(
    float* __restrict__ fused,
    const float* __restrict__ g1v, const float* __restrict__ b1v,
    const float* __restrict__ qw, const float* __restrict__ qb,
    const float* __restrict__ apw, const float* __restrict__ apb,
    const float* __restrict__ g2v, const float* __restrict__ b2v,
    const float* __restrict__ w1, const float* __restrict__ fb1,
    const float* __restrict__ w2, const float* __restrict__ fb2) {
    int tile = blockIdx.x, b = blockIdx.y;
    int n0 = tile * TR;
    int t = threadIdx.x;
    __shared__ float row[TE][ND];
    __shared__ float hh[TE][ND];
    __shared__ float qkvS[TE * 144];
    __shared__ float ob[TR][ND];
    __shared__ float nrow[TR][ND];
    __shared__ float mrs[TE][2];
    __shared__ float part[4][TR][ND];
    float* hid = qkvS;

    for (int i = t; i < TE * ND; i += 512) {
        int e = i / ND, c = i % ND;
        int n = n0 - 5 + e;
        row[e][c] = (n >= 0 && n < NSEQ) ? fused[((size_t)b * NSEQ + n) * ND + c] : 0.f;
    }
    __syncthreads();
    if (t < TE * 16) {
        int r = t >> 4, i = t & 15;
        float v0 = row[r][i], v1 = row[r][i + 16], v2 = row[r][i + 32];
        float s = v0 + v1 + v2;
        s += __shfl_down(s, 8, 16); s += __shfl_down(s, 4, 16);
        s += __shfl_down(s, 2, 16); s += __shfl_down(s, 1, 16);
        float m = __shfl(s, 0, 16) * (1.f / ND);
        float d0 = v0 - m, d1 = v1 - m, d2 = v2 - m;
        float q = d0 * d0 + d1 * d1 + d2 * d2;
        q += __shfl_down(q, 8, 16); q += __shfl_down(q, 4, 16);
        q += __shfl_down(q, 2, 16); q += __shfl_down(q, 1, 16);
        if (i == 0) { mrs[r][0] = m; mrs[r][1] = rsqrtf(q * (1.f / ND) + 1e-5f); }
    }
    __syncthreads();
    for (int i = t; i < TE * ND; i += 512) {
        int e = i / ND, c = i % ND;
        hh[e][c] = (row[e][c] - mrs[e][0]) * mrs[e][1] * g1v[c] + b1v[c];
    }
    __syncthreads();
    if (t < 288) {
        int col = t % 144, eg = t / 144;
        float w[ND];
        #pragma unroll
        for (int c = 0; c < ND; c++) w[c] = qw[c * 144 + col];
        float bias = qb[col];
        for (int e = eg * 9; e < eg * 9 + 9; e++) {
            float a = bias;
            #pragma unroll
            for (int c = 0; c < ND; c++) a += hh[e][c] * w[c];
            qkvS[e * 144 + col] = a;
        }
    }
    __syncthreads();
    if (t < TR * 8) {
        int r = t >> 3, h = t & 7;
        int n = n0 + r;
        if (n < NSEQ) {
            int k0 = n - 5; if (k0 < 0) k0 = 0;
            int k1 = n + 5; if (k1 > NSEQ - 1) k1 = NSEQ - 1;
            int nk = k1 - k0 + 1;
            float q[6];
            #pragma unroll
            for (int d = 0; d < 6; d++) q[d] = qkvS[(r + 5) * 144 + h * 6 + d];
            float sc[11];
            float mx = -1e30f;
            for (int ki = 0; ki < nk; ki++) {
                int e = k0 + ki - n0 + 5;
                float s = 0;
                #pragma unroll
                for (int d = 0; d < 6; d++) s += q[d] * qkvS[e * 144 + 48 + h * 6 + d];
                s *= 0.4082482904638631f;
                sc[ki] = s; mx = fmaxf(mx, s);
            }
            float sum = 0;
            for (int ki = 0; ki < nk; ki++) { float e = expf(sc[ki] - mx); sc[ki] = e; sum += e; }
            float inv = 1.f / sum;
            float o[6] = {0, 0, 0, 0, 0, 0};
            for (int ki = 0; ki < nk; ki++) {
                int e = k0 + ki - n0 + 5;
                float pv = sc[ki] * inv;
                #pragma unroll
                for (int d = 0; d < 6; d++) o[d] += pv * qkvS[e * 144 + 96 + h * 6 + d];
            }
            #pragma unroll
            for (int d = 0; d < 6; d++) ob[r][h * 6 + d] = o[d];
        } else {
            #pragma unroll
            for (int d = 0; d < 6; d++) ob[r][h * 6 + d] = 0.f;
        }
    }
    __syncthreads();
    if (t < TR * ND) {
        int r = t / ND, col = t % ND;
        float a = apb[col];
        #pragma unroll
        for (int c = 0; c < ND; c++) a += ob[r][c] * apw[c * ND + col];
        nrow[r][col] = row[r + 5][col] + a;
    }
    __syncthreads();
    if (t < TR * 16) {
        int r = t >> 4, i = t & 15;
        float v0 = nrow[r][i], v1 = nrow[r][i + 16], v2 = nrow[r][i + 32];
        float s = v0 + v1 + v2;
        s += __shfl_down(s, 8, 16); s += __shfl_down(s, 4, 16);
        s += __shfl_down(s, 2, 16); s += __shfl_down(s, 1, 16);
        float m = __shfl(s, 0, 16) * (1.f / ND);
        float d0 = v0 - m, d1 = v1 - m, d2 = v2 - m;
        float q = d0 * d0 + d1 * d1 + d2 * d2;
        q += __shfl_down(q, 8, 16); q += __shfl_down(q, 4, 16);
        q += __shfl_down(q, 2, 16); q += __shfl_down(q, 1, 16);
        if (i == 0) { mrs[r][0] = m; mrs[r][1] = rsqrtf(q * (1.f / ND) + 1e-5f); }
    }
    __syncthreads();
    if (t < TR * ND) {
        int r = t / ND, c = t % ND;
        hh[r][c] = (nrow[r][c] - mrs[r][0]) * mrs[r][1] * g2v[c] + b2v[c];
    }
    __syncthreads();
    if (t < 384) {
        int col = t % 192, rg = t / 192;
        float w[ND];
        #pragma unroll
        for (int c = 0; c < ND; c++) w[c] = w1[c * 192 + col];
        float bias = fb1[col];
        for (int r = rg * 4; r < rg * 4 + 4; r++) {
            float a = bias;
            #pragma unroll
            for (int c = 0; c < ND; c++) a += hh[r][c] * w[c];
            hid[r * 192 + col] = 0.5f * a * (1.f + erff(a * 0.70710678f));
        }
    }
    __syncthreads();
    if (t < 384) {
        int col = t % ND, kc = (t / ND) & 3, rh = t / 192;
        float w[ND];
        #pragma unroll
        for (int i2 = 0; i2 < ND; i2++) w[i2] = w2[(kc * ND + i2) * ND + col];
        for (int r = rh * 4; r < rh * 4 + 4; r++) {
            float a = 0;
            #pragma unroll
            for (int i2 = 0; i2 < ND; i2++) a += hid[r * 192 + kc * ND + i2] * w[i2];
            part[kc][r][col] = a;
        }
    }
    __syncthreads();
    for (int i = t; i < TR * ND; i += 512) {
        int r = i / ND, c = i % ND;
        int n = n0 + r;
        if (n < NSEQ) {
            fused[((size_t)b * NSEQ + n) * ND + c] =
                nrow[r][c] + fb2[c] + part[0][r][c] + part[1][r][c] + part[2][r][c] + part[3][r][c];
        }
    }
}

__global__ void k_head(const float* __restrict__ fused, const float* __restrict__ lg,
                       const float* __restrict__ lb, const float* __restrict__ cw,
                       const float* __restrict__ cb, float* __restrict__ out) {
    int b = blockIdx.x, t = threadIdx.x;
    __shared__ float part[4][ND];
    __shared__ float gg[ND], mv[2];
    if (t < 192) {
        int col = t % ND, qt = t / ND;
        int nA = qt * 63;
        int nB = (nA + 63 < NSEQ) ? nA + 63 : NSEQ;
        float s = 0.f;
        for (int n = nA; n < nB; n++) s += fused[((size_t)b * NSEQ + n) * ND + col];
        part[qt][col] = s;
    }
    __syncthreads();
    if (t < ND) gg[t] = (part[0][t] + part[1][t] + part[2][t] + part[3][t]) * (1.f / NSEQ);
    __syncthreads();
    if (t == 0) {
        float m = 0;
        for (int c = 0; c < ND; c++) m += gg[c];
        m /= (float)ND;
        float v = 0;
        for (int c = 0; c < ND; c++) { float dd = gg[c] - m; v += dd * dd; }
        v /= (float)ND;
        mv[0] = m; mv[1] = rsqrtf(v + 1e-5f);
    }
    __syncthreads();
    if (t < ND) gg[t] = (gg[t] - mv[0]) * mv[1] * lg[t] + lb[t];
    __syncthreads();
    if (t < 4) {
        float a = cb[t];
        for (int c = 0; c < ND; c++) a += gg[c] * cw[c * 4 + t];
        out[b * 4 + t] = a;
    }
}

extern "C" void kernel_launch(void* const* d_in, const int* in_sizes, int n_in,
                              void* d_out, int out_size, void* d_ws, size_t ws_size,
                              hipStream_t stream) {
    const float* x       = (const float*)d_in[0];
    const float* riem_w1 = (const float*)d_in[1];
    const float* riem_b1 = (const float*)d_in[2];
    const float* riem_w2 = (const float*)d_in[3];
    const float* riem_b2 = (const float*)d_in[4];
    const float* conv1_w = (const float*)d_in[5];
    const float* dw1_w   = (const float*)d_in[6];
    const float* dw2_w   = (const float*)d_in[7];
    const float* pw_w    = (const float*)d_in[8];
    const float* tc1_w   = (const float*)d_in[9];
    const float* tc1_b   = (const float*)d_in[10];
    const float* tc2_w   = (const float*)d_in[11];
    const float* tc2_b   = (const float*)d_in[12];
    const float* fusion  = (const float*)d_in[13];
    const float* pos_enc = (const float*)d_in[14];
    const float* ln1_g   = (const float*)d_in[15];
    const float* ln1_b   = (const float*)d_in[16];
    const float* qkv_w   = (const float*)d_in[17];
    const float* qkv_b   = (const float*)d_in[18];
    const float* apw     = (const float*)d_in[19];
    const float* apb     = (const float*)d_in[20];
    const float* ln2_g   = (const float*)d_in[21];
    const float* ln2_b   = (const float*)d_in[22];
    const float* ffn_w1  = (const float*)d_in[23];
    const float* ffn_b1  = (const float*)d_in[24];
    const float* ffn_w2  = (const float*)d_in[25];
    const float* ffn_b2  = (const float*)d_in[26];
    const float* cls_g   = (const float*)d_in[27];
    const float* cls_b_  = (const float*)d_in[28];
    const float* cls_w   = (const float*)d_in[29];
    const float* cls_bb  = (const float*)d_in[30];
    float* out = (float*)d_out;

    float* ws = (float*)d_ws;
    float* covS  = ws;                 // 4048
    float* sums  = ws + 4048;          // 352
    float* rfeat = ws + 4400;          // 768
    float* fused = ws + 5168;          // 192768
    float* pbuf  = ws + 197936;        // 1024000
    __hip_bfloat16* ybuf = (__hip_bfloat16*)(ws + 1221936); // 8192000 bf16

    hipMemsetAsync(covS, 0, 4400 * sizeof(float), stream);

    k_y<<<500, 256, 0, stream>>>(x, dw1_w, ybuf);
    k_covS<<<dim3(32, NB), 256, 0, stream>>>(x, covS, sums);
    k_cholfeat<<<NB, 256, 0, stream>>>(covS, sums, riem_w1, riem_b1, riem_w2, riem_b2, rfeat);

    k_conv64<<<dim3(4, 32, NB), 256, 0, stream>>>(ybuf, conv1_w, pbuf);
    k_stage2fuse<<<dim3(63, NB), 256, 0, stream>>>(pbuf, dw2_w, pw_w, rfeat,
                                                   tc1_w, tc1_b, tc2_w, tc2_b,
                                                   fusion, pos_enc, fused);

    for (int i = 0; i < 4; i++) {
        k_layer<<<dim3(32, NB), 512, 0, stream>>>(
            fused, ln1_g + i * 48, ln1_b + i * 48, qkv_w + i * 6912, qkv_b + i * 144,
            apw + i * 2304, apb + i * 48, ln2_g + i * 48, ln2_b + i * 48,
            ffn_w1 + i * 9216, ffn_b1 + i * 192, ffn_w2 + i * 9216, ffn_b2 + i * 48);
    }

    k_head<<<NB, 256, 0, stream>>>(fused, cls_g, cls_b_, cls_w, cls_bb, out);
}

// Round 10
// 293.976 us; speedup vs baseline: 1.0283x; 1.0156x over previous
//
#include <hip/hip_runtime.h>
#include <hip/hip_bf16.h>
#include <math.h>

#define BN_C 0.9999950000375f
#define NB 16
#define NC 22
#define NT 16000
#define NPAIR 253
#define NSEQ 251
#define ND 48
#define TR 8
#define TE 18

__device__ __forceinline__ unsigned short f2bf(float f) {
    union { float f; unsigned int u; } v; v.f = f;
    unsigned int r = v.u + 0x7fff + ((v.u >> 16) & 1);
    return (unsigned short)(r >> 16);
}
__device__ __forceinline__ float bf2f(unsigned short s) {
    union { unsigned int u; float f; } v; v.u = ((unsigned int)s) << 16;
    return v.f;
}

// ---------------- y production ----------------
__global__ __launch_bounds__(256) void k_y(const float* __restrict__ x,
                                           const float* __restrict__ dw1,
                                           __hip_bfloat16* __restrict__ y) {
    int gid = blockIdx.x * 256 + threadIdx.x; // 128000
    int b = gid / 8000, tp = gid % 8000;
    int t = tp * 2;
    const float* xb = x + (size_t)b * NC * NT + t;
    float a0[32], a1[32];
    #pragma unroll
    for (int j = 0; j < 32; j++) { a0[j] = 0.f; a1[j] = 0.f; }
    for (int h = 0; h < NC; h++) {
        float2 xv = *(const float2*)&xb[(size_t)h * NT];
        #pragma unroll
        for (int j = 0; j < 32; j++) {
            float w = dw1[j * NC + h];
            a0[j] += w * xv.x; a1[j] += w * xv.y;
        }
    }
    unsigned int* yo = (unsigned int*)(y + (size_t)b * 32 * NT + t);
    #pragma unroll
    for (int j = 0; j < 32; j++) {
        unsigned int pk = (unsigned int)f2bf(a0[j]) | ((unsigned int)f2bf(a1[j]) << 16);
        yo[j * (NT / 2)] = pk;
    }
}

// ---------------- Riemannian branch ----------------
// cov sums via atomics into dense covS/sums (must be zeroed): grid dim3(32,16), block 256
#define TCHUNK 500
#define XROW 504
__global__ __launch_bounds__(256) void k_covS(const float* __restrict__ x,
                                              float* __restrict__ covS,
                                              float* __restrict__ sums) {
    int chunk = blockIdx.x, b = blockIdx.y;
    int t0 = chunk * TCHUNK;
    __shared__ unsigned short xs[NC * XROW];
    const float* xp = x + (size_t)b * NC * NT + t0;
    for (int i = threadIdx.x; i < NC * 126; i += 256) {
        int c = i / 126, q = i % 126;
        unsigned long long pk = 0ull;
        if (q < 125) {
            float4 v = *(const float4*)&xp[(size_t)c * NT + 4 * q];
            pk = (unsigned long long)f2bf(v.x) | ((unsigned long long)f2bf(v.y) << 16)
               | ((unsigned long long)f2bf(v.z) << 32) | ((unsigned long long)f2bf(v.w) << 48);
        }
        *(unsigned long long*)&xs[c * XROW + 4 * q] = pk;
    }
    __syncthreads();
    int p = threadIdx.x;
    if (p < NPAIR) {
        int c = 0, r = p;
        while (r >= NC - c) { r -= NC - c; c++; }
        int d = c + r;
        const unsigned short* xc = &xs[c * XROW];
        const unsigned short* xd = &xs[d * XROW];
        float a0 = 0, a1 = 0, a2 = 0, a3 = 0;
        float s0 = 0, s1 = 0, s2 = 0, s3 = 0;
        for (int t = 0; t < XROW; t += 8) {
            uint4 pc = *(const uint4*)&xc[t];
            uint4 pd = *(const uint4*)&xd[t];
            float c0 = bf2f((unsigned short)pc.x), c1 = bf2f((unsigned short)(pc.x >> 16));
            float c2 = bf2f((unsigned short)pc.y), c3 = bf2f((unsigned short)(pc.y >> 16));
            float c4 = bf2f((unsigned short)pc.z), c5 = bf2f((unsigned short)(pc.z >> 16));
            float c6 = bf2f((unsigned short)pc.w), c7 = bf2f((unsigned short)(pc.w >> 16));
            float d0 = bf2f((unsigned short)pd.x), d1 = bf2f((unsigned short)(pd.x >> 16));
            float d2 = bf2f((unsigned short)pd.y), d3 = bf2f((unsigned short)(pd.y >> 16));
            float d4 = bf2f((unsigned short)pd.z), d5 = bf2f((unsigned short)(pd.z >> 16));
            float d6 = bf2f((unsigned short)pd.w), d7 = bf2f((unsigned short)(pd.w >> 16));
            a0 += c0 * d0 + c4 * d4; a1 += c1 * d1 + c5 * d5;
            a2 += c2 * d2 + c6 * d6; a3 += c3 * d3 + c7 * d7;
            s0 += c0 + c4; s1 += c1 + c5; s2 += c2 + c6; s3 += c3 + c7;
        }
        atomicAdd(&covS[b * NPAIR + p], (a0 + a1) + (a2 + a3));
        if (c == d) atomicAdd(&sums[b * NC + c], (s0 + s1) + (s2 + s3));
    }
}

// dense covS -> cov(LDS) + trace + register Cholesky + MLP: grid 16, block 256
__global__ __launch_bounds__(256) void k_cholfeat(
    const float* __restrict__ covS, const float* __restrict__ sums,
    const float* __restrict__ w1, const float* __restrict__ b1,
    const float* __restrict__ w2, const float* __restrict__ b2,
    float* __restrict__ rfeat) {
    int b = blockIdx.x, t = threadIdx.x;
    __shared__ float covL[484];
    __shared__ float trS[NB];
    __shared__ float dvs[NC];
    __shared__ float hid[256];
    __shared__ float part[4][ND];
    if (t < NB) trS[t] = 0.f;
    __syncthreads();
    if (t < NPAIR) {
        int c = 0, r = t;
        while (r >= NC - c) { r -= NC - c; c++; }
        int d = c + r;
        float v = (covS[b * NPAIR + t] - sums[b * NC + c] * sums[b * NC + d] / (float)NT)
                  / (float)(NT - 1);
        if (c == d) v += 1e-5f;
        covL[c * NC + d] = v;
        covL[d * NC + c] = v;
    }
    for (int i = t; i < NB * NC; i += 256) {
        int bb = i / NC, c = i % NC;
        int pos = c * NC - c * (c - 1) / 2;
        float sc = sums[bb * NC + c];
        float v = (covS[bb * NPAIR + pos] - sc * sc / (float)NT) / (float)(NT - 1) + 1e-5f;
        atomicAdd(&trS[bb], v);
    }
    __syncthreads();
    float trs = 0.f;
    for (int i = 0; i < NB; i++) trs += trS[i];
    float trm = trs * (0.001f / (float)NB);
    if (t < 64) {
        int lane = t;
        float a[NC];
        #pragma unroll
        for (int j = 0; j < NC; j++) {
            float v = (lane < NC) ? covL[lane * NC + j] : 0.f;
            a[j] = v + ((j == lane) ? trm : 0.f);
        }
        float diagv = 1.f;
        #pragma unroll
        for (int k = 0; k < NC; k++) {
            float akk = __shfl(a[k], k);
            float dk = sqrtf(akk);
            if (lane == k) { a[k] = dk; diagv = dk; }
            else if (lane > k) a[k] /= dk;
            float myak = a[k];
            #pragma unroll
            for (int j = k + 1; j < NC; j++) {
                float ljk = __shfl(myak, j);
                if (lane >= j) a[j] -= myak * ljk;
            }
        }
        if (lane < NC) dvs[lane] = diagv * logf(fmaxf(diagv, 1e-10f));
    }
    __syncthreads();
    {
        float acc = b1[t];
        #pragma unroll
        for (int d = 0; d < NC; d++) {
            int pos = d * NC - d * (d - 1) / 2;
            acc += dvs[d] * w1[pos * 256 + t];
        }
        hid[t] = (acc > 0.f) ? acc : expm1f(acc);
    }
    __syncthreads();
    if (t < 192) {
        int col = t % ND, kc = t / ND;
        float a = 0.f;
        #pragma unroll
        for (int i = 0; i < 64; i++) a += hid[kc * 64 + i] * w2[(kc * 64 + i) * ND + col];
        part[kc][col] = a;
    }
    __syncthreads();
    if (t < ND)
        rfeat[b * ND + t] = b2[t] + part[0][t] + part[1][t] + part[2][t] + part[3][t];
}

// ---------------- Conv branch (round-6 version: 1 output/thread) ----------------
#define UT 256
__global__ __launch_bounds__(256) void k_conv64(const __hip_bfloat16* __restrict__ y,
                                                const float* __restrict__ c1w,
                                                float* __restrict__ p) {
    int tile = blockIdx.x, j = blockIdx.y, b = blockIdx.z;
    int u0 = tile * UT;
    __shared__ float yt[2376];
    const __hip_bfloat16* yp = y + ((size_t)(b * 32 + j)) * NT;
    int tbase = u0 * 8 - 32;
    for (int q = threadIdx.x; q < 1056; q += 256) {
        int i = 2 * q;
        int tq = tbase + i;
        float v0 = 0.f, v1 = 0.f;
        if (tq >= 0 && tq + 1 < NT) {
            unsigned int pk = *(const unsigned int*)(yp + tq);
            v0 = bf2f((unsigned short)pk); v1 = bf2f((unsigned short)(pk >> 16));
        } else {
            if (tq >= 0 && tq < NT) v0 = __bfloat162float(yp[tq]);
            if (tq + 1 >= 0 && tq + 1 < NT) v1 = __bfloat162float(yp[tq + 1]);
        }
        yt[i + (i >> 3)] = v0;
        int i1 = i + 1;
        yt[i1 + (i1 >> 3)] = v1;
    }
    __syncthreads();
    const float* cf = c1w + (j >> 1) * 64;
    int u = u0 + threadIdx.x;
    if (u < 2000) {
        int off = 8 * threadIdx.x;
        float acc[8];
        #pragma unroll
        for (int s = 0; s < 8; s++) acc[s] = 0.f;
        #pragma unroll
        for (int kb = 0; kb < 64; kb += 16) {
            float Yb[23];
            #pragma unroll
            for (int m = 0; m < 23; m++) {
                int idx = off + kb + m;
                Yb[m] = yt[idx + (idx >> 3)];
            }
            #pragma unroll
            for (int k = 0; k < 16; k++) {
                float c = cf[kb + k];
                #pragma unroll
                for (int s = 0; s < 8; s++) acc[s] += c * Yb[k + s];
            }
        }
        const float bn2 = BN_C * BN_C;
        float pv = 0.f;
        #pragma unroll
        for (int s = 0; s < 8; s++) {
            float z = bn2 * acc[s];
            pv += (z > 0.f) ? z : expm1f(z);
        }
        p[((size_t)(b * 32 + j)) * 2000 + u] = pv * 0.125f;
    }
}

// ---------------- stage2 (round-6): 4 u2 per block ----------------
__global__ __launch_bounds__(256) void k_stage2(const float* __restrict__ p,
                                                const float* __restrict__ dw2,
                                                const float* __restrict__ pw,
                                                float* __restrict__ feat) {
    int u2b = blockIdx.x * 4, b = blockIdx.y, t = threadIdx.x;
    __shared__ float pt[32][48];
    __shared__ float dval[32][32];
    __shared__ float w2s[512];
    __shared__ float pws[1536];
    for (int i = t; i < 512; i += 256) w2s[i] = dw2[i];
    for (int i = t; i < 1536; i += 256) pws[i] = pw[i];
    int base = 8 * u2b - 8;
    for (int i = t; i < 32 * 47; i += 256) {
        int j = i / 47, tt = i % 47;
        int gt = base + tt;
        pt[j][tt] = (gt >= 0 && gt < 2000) ? p[((size_t)(b * 32 + j)) * 2000 + gt] : 0.f;
    }
    __syncthreads();
    for (int i = t; i < 1024; i += 256) {
        int j = i >> 5, su = i & 31;
        int u = su >> 3, s = su & 7;
        float a = 0.f;
        #pragma unroll
        for (int k = 0; k < 16; k++) a += w2s[j * 16 + k] * pt[j][8 * u + s + k];
        dval[j][su] = a * BN_C;
    }
    __syncthreads();
    if (t < 192) {
        int col = t % ND, u = t / ND;
        int u2 = u2b + u;
        if (u2 < 250) {
            float wreg[32];
            #pragma unroll
            for (int j = 0; j < 32; j++) wreg[j] = pws[col * 32 + j];
            float acc = 0.f;
            #pragma unroll
            for (int s = 0; s < 8; s++) {
                float e = 0.f;
                #pragma unroll
                for (int j = 0; j < 32; j++) e += wreg[j] * dval[j][u * 8 + s];
                e *= BN_C;
                acc += (e > 0.f) ? e : expm1f(e);
            }
            feat[((size_t)b * 250 + u2) * ND + col] = acc * 0.125f;
        }
    }
}

// ---------------- fuse (round-6) ----------------
__global__ __launch_bounds__(256) void k_fuse(
    const float* __restrict__ feat, const float* __restrict__ rfeat,
    const float* __restrict__ tc1w, const float* __restrict__ tc1b,
    const float* __restrict__ tc2w, const float* __restrict__ tc2b,
    const float* __restrict__ fp, const float* __restrict__ pe,
    float* __restrict__ fused) {
    int b = blockIdx.y;
    int sub = threadIdx.x >> 6, lt = threadIdx.x & 63;
    int n = blockIdx.x * 4 + sub;
    bool valid = (n < NSEQ);
    __shared__ float row[4][ND];
    __shared__ float g1[4][24];
    if (valid) {
        if (n == 0) {
            if (lt < ND) row[sub][lt] = rfeat[b * ND + lt];
        } else {
            int u = n - 1;
            if (lt < 24) {
                int m = lt;
                float a = tc1b[m];
                #pragma unroll
                for (int k = 0; k < 3; k++) {
                    int uu = u + k - 1;
                    if (uu >= 0 && uu < 250) {
                        float f0 = feat[((size_t)b * 250 + uu) * ND + 2 * m];
                        float f1 = feat[((size_t)b * 250 + uu) * ND + 2 * m + 1];
                        a += tc1w[m * 6 + k] * f0 + tc1w[m * 6 + 3 + k] * f1;
                    }
                }
                float z = a * BN_C;
                g1[sub][m] = 0.5f * z * (1.f + erff(z * 0.70710678f));
            }
        }
    }
    __syncthreads();
    if (valid && n > 0 && lt < ND) {
        int u = n - 1;
        float a = tc2b[lt];
        #pragma unroll
        for (int m = 0; m < 24; m++) a += tc2w[lt * 24 + m] * g1[sub][m];
        row[sub][lt] = feat[((size_t)b * 250 + u) * ND + lt] + a;
    }
    __syncthreads();
    if (valid && lt < ND) {
        float o = pe[n * ND + lt];
        for (int c = 0; c < ND; c++) o += row[sub][c] * fp[c * ND + lt];
        fused[((size_t)b * NSEQ + n) * ND + lt] = o;
    }
}

// ---------------- Fused transformer layer: block 512 ----------------
__global__ __launch_bounds__(512) void k_layer(
    float* __restrict__ fused,
    const float* __restrict__ g1v, const float* __restrict__ b1v,
    const float* __restrict__ qw, const float* __restrict__ qb,
    const float* __restrict__ apw, const float* __restrict__ apb,
    const float* __restrict__ g2v, const float* __restrict__ b2v,
    const float* __restrict__ w1, const float* __restrict__ fb1,
    const float* __restrict__ w2, const float* __restrict__ fb2) {
    int tile = blockIdx.x, b = blockIdx.y;
    int n0 = tile * TR;
    int t = threadIdx.x;
    __shared__ float row[TE][ND];
    __shared__ float hh[TE][ND];
    __shared__ float qkvS[TE * 144];
    __shared__ float ob[TR][ND];
    __shared__ float nrow[TR][ND];
    __shared__ float mrs[TE][2];
    __shared__ float part[4][TR][ND];
    float* hid = qkvS;

    for (int i = t; i < TE * ND; i += 512) {
        int e = i / ND, c = i % ND;
        int n = n0 - 5 + e;
        row[e][c] = (n >= 0 && n < NSEQ) ? fused[((size_t)b * NSEQ + n) * ND + c] : 0.f;
    }
    __syncthreads();
    if (t < TE * 16) {
        int r = t >> 4, i = t & 15;
        float v0 = row[r][i], v1 = row[r][i + 16], v2 = row[r][i + 32];
        float s = v0 + v1 + v2;
        s += __shfl_down(s, 8, 16); s += __shfl_down(s, 4, 16);
        s += __shfl_down(s, 2, 16); s += __shfl_down(s, 1, 16);
        float m = __shfl(s, 0, 16) * (1.f / ND);
        float d0 = v0 - m, d1 = v1 - m, d2 = v2 - m;
        float q = d0 * d0 + d1 * d1 + d2 * d2;
        q += __shfl_down(q, 8, 16); q += __shfl_down(q, 4, 16);
        q += __shfl_down(q, 2, 16); q += __shfl_down(q, 1, 16);
        if (i == 0) { mrs[r][0] = m; mrs[r][1] = rsqrtf(q * (1.f / ND) + 1e-5f); }
    }
    __syncthreads();
    for (int i = t; i < TE * ND; i += 512) {
        int e = i / ND, c = i % ND;
        hh[e][c] = (row[e][c] - mrs[e][0]) * mrs[e][1] * g1v[c] + b1v[c];
    }
    __syncthreads();
    if (t < 288) {
        int col = t % 144, eg = t / 144;
        float w[ND];
        #pragma unroll
        for (int c = 0; c < ND; c++) w[c] = qw[c * 144 + col];
        float bias = qb[col];
        for (int e = eg * 9; e < eg * 9 + 9; e++) {
            float a = bias;
            #pragma unroll
            for (int c = 0; c < ND; c++) a += hh[e][c] * w[c];
            qkvS[e * 144 + col] = a;
        }
    }
    __syncthreads();
    if (t < TR * 8) {
        int r = t >> 3, h = t & 7;
        int n = n0 + r;
        if (n < NSEQ) {
            int k0 = n - 5; if (k0 < 0) k0 = 0;
            int k1 = n + 5; if (k1 > NSEQ - 1) k1 = NSEQ - 1;
            int nk = k1 - k0 + 1;
            float q[6];
            #pragma unroll
            for (int d = 0; d < 6; d++) q[d] = qkvS[(r + 5) * 144 + h * 6 + d];
            float sc[11];
            float mx = -1e30f;
            for (int ki = 0; ki < nk; ki++) {
                int e = k0 + ki - n0 + 5;
                float s = 0;
                #pragma unroll
                for (int d = 0; d < 6; d++) s += q[d] * qkvS[e * 144 + 48 + h * 6 + d];
                s *= 0.4082482904638631f;
                sc[ki] = s; mx = fmaxf(mx, s);
            }
            float sum = 0;
            for (int ki = 0; ki < nk; ki++) { float e = expf(sc[ki] - mx); sc[ki] = e; sum += e; }
            float inv = 1.f / sum;
            float o[6] = {0, 0, 0, 0, 0, 0};
            for (int ki = 0; ki < nk; ki++) {
                int e = k0 + ki - n0 + 5;
                float pv = sc[ki] * inv;
                #pragma unroll
                for (int d = 0; d < 6; d++) o[d] += pv * qkvS[e * 144 + 96 + h * 6 + d];
            }
            #pragma unroll
            for (int d = 0; d < 6; d++) ob[r][h * 6 + d] = o[d];
        } else {
            #pragma unroll
            for (int d = 0; d < 6; d++) ob[r][h * 6 + d] = 0.f;
        }
    }
    __syncthreads();
    if (t < TR * ND) {
        int r = t / ND, col = t % ND;
        float a = apb[col];
        #pragma unroll
        for (int c = 0; c < ND; c++) a += ob[r][c] * apw[c * ND + col];
        nrow[r][col] = row[r + 5][col] + a;
    }
    __syncthreads();
    if (t < TR * 16) {
        int r = t >> 4, i = t & 15;
        float v0 = nrow[r][i], v1 = nrow[r][i + 16], v2 = nrow[r][i + 32];
        float s = v0 + v1 + v2;
        s += __shfl_down(s, 8, 16); s += __shfl_down(s, 4, 16);
        s += __shfl_down(s, 2, 16); s += __shfl_down(s, 1, 16);
        float m = __shfl(s, 0, 16) * (1.f / ND);
        float d0 = v0 - m, d1 = v1 - m, d2 = v2 - m;
        float q = d0 * d0 + d1 * d1 + d2 * d2;
        q += __shfl_down(q, 8, 16); q += __shfl_down(q, 4, 16);
        q += __shfl_down(q, 2, 16); q += __shfl_down(q, 1, 16);
        if (i == 0) { mrs[r][0] = m; mrs[r][1] = rsqrtf(q * (1.f / ND) + 1e-5f); }
    }
    __syncthreads();
    if (t < TR * ND) {
        int r = t / ND, c = t % ND;
        hh[r][c] = (nrow[r][c] - mrs[r][0]) * mrs[r][1] * g2v[c] + b2v[c];
    }
    __syncthreads();
    if (t < 384) {
        int col = t % 192, rg = t / 192;
        float w[ND];
        #pragma unroll
        for (int c = 0; c < ND; c++) w[c] = w1[c * 192 + col];
        float bias = fb1[col];
        for (int r = rg * 4; r < rg * 4 + 4; r++) {
            float a = bias;
            #pragma unroll
            for (int c = 0; c < ND; c++) a += hh[r][c] * w[c];
            hid[r * 192 + col] = 0.5f * a * (1.f + erff(a * 0.70710678f));
        }
    }
    __syncthreads();
    if (t < 384) {
        int col = t % ND, kc = (t / ND) & 3, rh = t / 192;
        float w[ND];
        #pragma unroll
        for (int i2 = 0; i2 < ND; i2++) w[i2] = w2[(kc * ND + i2) * ND + col];
        for (int r = rh * 4; r < rh * 4 + 4; r++) {
            float a = 0;
            #pragma unroll
            for (int i2 = 0; i2 < ND; i2++) a += hid[r * 192 + kc * ND + i2] * w[i2];
            part[kc][r][col] = a;
        }
    }
    __syncthreads();
    for (int i = t; i < TR * ND; i += 512) {
        int r = i / ND, c = i % ND;
        int n = n0 + r;
        if (n < NSEQ) {
            fused[((size_t)b * NSEQ + n) * ND + c] =
                nrow[r][c] + fb2[c] + part[0][r][c] + part[1][r][c] + part[2][r][c] + part[3][r][c];
        }
    }
}

__global__ void k_head(const float* __restrict__ fused, const float* __restrict__ lg,
                       const float* __restrict__ lb, const float* __restrict__ cw,
                       const float* __restrict__ cb, float* __restrict__ out) {
    int b = blockIdx.x, t = threadIdx.x;
    __shared__ float part[4][ND];
    __shared__ float gg[ND], mv[2];
    if (t < 192) {
        int col = t % ND, qt = t / ND;
        int nA = qt * 63;
        int nB = (nA + 63 < NSEQ) ? nA + 63 : NSEQ;
        float s = 0.f;
        for (int n = nA; n < nB; n++) s += fused[((size_t)b * NSEQ + n) * ND + col];
        part[qt][col] = s;
    }
    __syncthreads();
    if (t < ND) gg[t] = (part[0][t] + part[1][t] + part[2][t] + part[3][t]) * (1.f / NSEQ);
    __syncthreads();
    if (t == 0) {
        float m = 0;
        for (int c = 0; c < ND; c++) m += gg[c];
        m /= (float)ND;
        float v = 0;
        for (int c = 0; c < ND; c++) { float dd = gg[c] - m; v += dd * dd; }
        v /= (float)ND;
        mv[0] = m; mv[1] = rsqrtf(v + 1e-5f);
    }
    __syncthreads();
    if (t < ND) gg[t] = (gg[t] - mv[0]) * mv[1] * lg[t] + lb[t];
    __syncthreads();
    if (t < 4) {
        float a = cb[t];
        for (int c = 0; c < ND; c++) a += gg[c] * cw[c * 4 + t];
        out[b * 4 + t] = a;
    }
}

extern "C" void kernel_launch(void* const* d_in, const int* in_sizes, int n_in,
                              void* d_out, int out_size, void* d_ws, size_t ws_size,
                              hipStream_t stream) {
    const float* x       = (const float*)d_in[0];
    const float* riem_w1 = (const float*)d_in[1];
    const float* riem_b1 = (const float*)d_in[2];
    const float* riem_w2 = (const float*)d_in[3];
    const float* riem_b2 = (const float*)d_in[4];
    const float* conv1_w = (const float*)d_in[5];
    const float* dw1_w   = (const float*)d_in[6];
    const float* dw2_w   = (const float*)d_in[7];
    const float* pw_w    = (const float*)d_in[8];
    const float* tc1_w   = (const float*)d_in[9];
    const float* tc1_b   = (const float*)d_in[10];
    const float* tc2_w   = (const float*)d_in[11];
    const float* tc2_b   = (const float*)d_in[12];
    const float* fusion  = (const float*)d_in[13];
    const float* pos_enc = (const float*)d_in[14];
    const float* ln1_g   = (const float*)d_in[15];
    const float* ln1_b   = (const float*)d_in[16];
    const float* qkv_w   = (const float*)d_in[17];
    const float* qkv_b   = (const float*)d_in[18];
    const float* apw     = (const float*)d_in[19];
    const float* apb     = (const float*)d_in[20];
    const float* ln2_g   = (const float*)d_in[21];
    const float* ln2_b   = (const float*)d_in[22];
    const float* ffn_w1  = (const float*)d_in[23];
    const float* ffn_b1  = (const float*)d_in[24];
    const float* ffn_w2  = (const float*)d_in[25];
    const float* ffn_b2  = (const float*)d_in[26];
    const float* cls_g   = (const float*)d_in[27];
    const float* cls_b_  = (const float*)d_in[28];
    const float* cls_w   = (const float*)d_in[29];
    const float* cls_bb  = (const float*)d_in[30];
    float* out = (float*)d_out;

    float* ws = (float*)d_ws;
    float* covS  = ws;                 // 4048
    float* sums  = ws + 4048;          // 352
    float* rfeat = ws + 4400;          // 768
    float* feat  = ws + 5168;          // 192000
    float* fused = ws + 197168;        // 192768
    float* pbuf  = ws + 389936;        // 1024000
    __hip_bfloat16* ybuf = (__hip_bfloat16*)(ws + 1413936); // 8192000 bf16

    hipMemsetAsync(covS, 0, 4400 * sizeof(float), stream);

    k_y<<<500, 256, 0, stream>>>(x, dw1_w, ybuf);
    k_covS<<<dim3(32, NB), 256, 0, stream>>>(x, covS, sums);
    k_cholfeat<<<NB, 256, 0, stream>>>(covS, sums, riem_w1, riem_b1, riem_w2, riem_b2, rfeat);

    k_conv64<<<dim3(8, 32, NB), 256, 0, stream>>>(ybuf, conv1_w, pbuf);
    k_stage2<<<dim3(63, NB), 256, 0, stream>>>(pbuf, dw2_w, pw_w, feat);
    k_fuse<<<dim3(63, NB), 256, 0, stream>>>(feat, rfeat, tc1_w, tc1_b, tc2_w, tc2_b,
                                             fusion, pos_enc, fused);

    for (int i = 0; i < 4; i++) {
        k_layer<<<dim3(32, NB), 512, 0, stream>>>(
            fused, ln1_g + i * 48, ln1_b + i * 48, qkv_w + i * 6912, qkv_b + i * 144,
            apw + i * 2304, apb + i * 48, ln2_g + i * 48, ln2_b + i * 48,
            ffn_w1 + i * 9216, ffn_b1 + i * 192, ffn_w2 + i * 9216, ffn_b2 + i * 48);
    }

    k_head<<<NB, 256, 0, stream>>>(fused, cls_g, cls_b_, cls_w, cls_bb, out);
}

// Round 11
// 288.743 us; speedup vs baseline: 1.0470x; 1.0181x over previous
//
#include <hip/hip_runtime.h>
#include <hip/hip_bf16.h>
#include <math.h>

#define BN_C 0.9999950000375f
#define NB 16
#define NC 22
#define NT 16000
#define NPAIR 253
#define NSEQ 251
#define ND 48
#define TR 8
#define TE 18

__device__ __forceinline__ unsigned short f2bf(float f) {
    union { float f; unsigned int u; } v; v.f = f;
    unsigned int r = v.u + 0x7fff + ((v.u >> 16) & 1);
    return (unsigned short)(r >> 16);
}
__device__ __forceinline__ float bf2f(unsigned short s) {
    union { unsigned int u; float f; } v; v.u = ((unsigned int)s) << 16;
    return v.f;
}

// ---------------- y production ----------------
__global__ __launch_bounds__(256) void k_y(const float* __restrict__ x,
                                           const float* __restrict__ dw1,
                                           __hip_bfloat16* __restrict__ y) {
    int gid = blockIdx.x * 256 + threadIdx.x; // 128000
    int b = gid / 8000, tp = gid % 8000;
    int t = tp * 2;
    const float* xb = x + (size_t)b * NC * NT + t;
    float a0[32], a1[32];
    #pragma unroll
    for (int j = 0; j < 32; j++) { a0[j] = 0.f; a1[j] = 0.f; }
    for (int h = 0; h < NC; h++) {
        float2 xv = *(const float2*)&xb[(size_t)h * NT];
        #pragma unroll
        for (int j = 0; j < 32; j++) {
            float w = dw1[j * NC + h];
            a0[j] += w * xv.x; a1[j] += w * xv.y;
        }
    }
    unsigned int* yo = (unsigned int*)(y + (size_t)b * 32 * NT + t);
    #pragma unroll
    for (int j = 0; j < 32; j++) {
        unsigned int pk = (unsigned int)f2bf(a0[j]) | ((unsigned int)f2bf(a1[j]) << 16);
        yo[j * (NT / 2)] = pk;
    }
}

// ---------------- Riemannian branch ----------------
#define TCHUNK 500
#define XROW 504
__global__ __launch_bounds__(256) void k_covS(const float* __restrict__ x,
                                              float* __restrict__ covS,
                                              float* __restrict__ sums) {
    int chunk = blockIdx.x, b = blockIdx.y;
    int t0 = chunk * TCHUNK;
    __shared__ unsigned short xs[NC * XROW];
    const float* xp = x + (size_t)b * NC * NT + t0;
    for (int i = threadIdx.x; i < NC * 126; i += 256) {
        int c = i / 126, q = i % 126;
        unsigned long long pk = 0ull;
        if (q < 125) {
            float4 v = *(const float4*)&xp[(size_t)c * NT + 4 * q];
            pk = (unsigned long long)f2bf(v.x) | ((unsigned long long)f2bf(v.y) << 16)
               | ((unsigned long long)f2bf(v.z) << 32) | ((unsigned long long)f2bf(v.w) << 48);
        }
        *(unsigned long long*)&xs[c * XROW + 4 * q] = pk;
    }
    __syncthreads();
    int p = threadIdx.x;
    if (p < NPAIR) {
        int c = 0, r = p;
        while (r >= NC - c) { r -= NC - c; c++; }
        int d = c + r;
        const unsigned short* xc = &xs[c * XROW];
        const unsigned short* xd = &xs[d * XROW];
        float a0 = 0, a1 = 0, a2 = 0, a3 = 0;
        float s0 = 0, s1 = 0, s2 = 0, s3 = 0;
        for (int t = 0; t < XROW; t += 8) {
            uint4 pc = *(const uint4*)&xc[t];
            uint4 pd = *(const uint4*)&xd[t];
            float c0 = bf2f((unsigned short)pc.x), c1 = bf2f((unsigned short)(pc.x >> 16));
            float c2 = bf2f((unsigned short)pc.y), c3 = bf2f((unsigned short)(pc.y >> 16));
            float c4 = bf2f((unsigned short)pc.z), c5 = bf2f((unsigned short)(pc.z >> 16));
            float c6 = bf2f((unsigned short)pc.w), c7 = bf2f((unsigned short)(pc.w >> 16));
            float d0 = bf2f((unsigned short)pd.x), d1 = bf2f((unsigned short)(pd.x >> 16));
            float d2 = bf2f((unsigned short)pd.y), d3 = bf2f((unsigned short)(pd.y >> 16));
            float d4 = bf2f((unsigned short)pd.z), d5 = bf2f((unsigned short)(pd.z >> 16));
            float d6 = bf2f((unsigned short)pd.w), d7 = bf2f((unsigned short)(pd.w >> 16));
            a0 += c0 * d0 + c4 * d4; a1 += c1 * d1 + c5 * d5;
            a2 += c2 * d2 + c6 * d6; a3 += c3 * d3 + c7 * d7;
            s0 += c0 + c4; s1 += c1 + c5; s2 += c2 + c6; s3 += c3 + c7;
        }
        atomicAdd(&covS[b * NPAIR + p], (a0 + a1) + (a2 + a3));
        if (c == d) atomicAdd(&sums[b * NC + c], (s0 + s1) + (s2 + s3));
    }
}

// dense covS -> cov(LDS) + trace + register Cholesky + MLP: grid 16, block 256
__global__ __launch_bounds__(256) void k_cholfeat(
    const float* __restrict__ covS, const float* __restrict__ sums,
    const float* __restrict__ w1, const float* __restrict__ b1,
    const float* __restrict__ w2, const float* __restrict__ b2,
    float* __restrict__ rfeat) {
    int b = blockIdx.x, t = threadIdx.x;
    __shared__ float covL[484];
    __shared__ float trS[NB];
    __shared__ float dvs[NC];
    __shared__ float hid[256];
    __shared__ float part[4][ND];
    if (t < NB) trS[t] = 0.f;
    __syncthreads();
    if (t < NPAIR) {
        int c = 0, r = t;
        while (r >= NC - c) { r -= NC - c; c++; }
        int d = c + r;
        float v = (covS[b * NPAIR + t] - sums[b * NC + c] * sums[b * NC + d] / (float)NT)
                  / (float)(NT - 1);
        if (c == d) v += 1e-5f;
        covL[c * NC + d] = v;
        covL[d * NC + c] = v;
    }
    for (int i = t; i < NB * NC; i += 256) {
        int bb = i / NC, c = i % NC;
        int pos = c * NC - c * (c - 1) / 2;
        float sc = sums[bb * NC + c];
        float v = (covS[bb * NPAIR + pos] - sc * sc / (float)NT) / (float)(NT - 1) + 1e-5f;
        atomicAdd(&trS[bb], v);
    }
    __syncthreads();
    float trs = 0.f;
    for (int i = 0; i < NB; i++) trs += trS[i];
    float trm = trs * (0.001f / (float)NB);
    if (t < 64) {
        int lane = t;
        float a[NC];
        #pragma unroll
        for (int j = 0; j < NC; j++) {
            float v = (lane < NC) ? covL[lane * NC + j] : 0.f;
            a[j] = v + ((j == lane) ? trm : 0.f);
        }
        float diagv = 1.f;
        #pragma unroll
        for (int k = 0; k < NC; k++) {
            float akk = __shfl(a[k], k);
            float dk = sqrtf(akk);
            if (lane == k) { a[k] = dk; diagv = dk; }
            else if (lane > k) a[k] /= dk;
            float myak = a[k];
            #pragma unroll
            for (int j = k + 1; j < NC; j++) {
                float ljk = __shfl(myak, j);
                if (lane >= j) a[j] -= myak * ljk;
            }
        }
        if (lane < NC) dvs[lane] = diagv * logf(fmaxf(diagv, 1e-10f));
    }
    __syncthreads();
    {
        float acc = b1[t];
        #pragma unroll
        for (int d = 0; d < NC; d++) {
            int pos = d * NC - d * (d - 1) / 2;
            acc += dvs[d] * w1[pos * 256 + t];
        }
        hid[t] = (acc > 0.f) ? acc : expm1f(acc);
    }
    __syncthreads();
    if (t < 192) {
        int col = t % ND, kc = t / ND;
        float a = 0.f;
        #pragma unroll
        for (int i = 0; i < 64; i++) a += hid[kc * 64 + i] * w2[(kc * 64 + i) * ND + col];
        part[kc][col] = a;
    }
    __syncthreads();
    if (t < ND)
        rfeat[b * ND + t] = b2[t] + part[0][t] + part[1][t] + part[2][t] + part[3][t];
}

// ---------------- Conv branch: XOR-swizzled float4 LDS, b128 reads ----------------
// yt stored as 528 float4 blocks; block w lives at w ^ ((w>>3)&1).
#define UT 256
__global__ __launch_bounds__(256) void k_conv64(const __hip_bfloat16* __restrict__ y,
                                                const float* __restrict__ c1w,
                                                float* __restrict__ p) {
    int tile = blockIdx.x, j = blockIdx.y, b = blockIdx.z;
    int u0 = tile * UT;
    __shared__ float4 yt4[528]; // 2112 floats, swizzled
    const __hip_bfloat16* yp = y + ((size_t)(b * 32 + j)) * NT;
    int tbase = u0 * 8 - 32;
    for (int w = threadIdx.x; w < 528; w += 256) {
        int tq = tbase + 4 * w;
        float4 v;
        if (tq >= 0 && tq + 3 < NT) {
            uint2 pk = *(const uint2*)(yp + tq); // 4 bf16, 8B aligned
            v.x = bf2f((unsigned short)pk.x); v.y = bf2f((unsigned short)(pk.x >> 16));
            v.z = bf2f((unsigned short)pk.y); v.w = bf2f((unsigned short)(pk.y >> 16));
        } else {
            v.x = (tq >= 0 && tq < NT) ? __bfloat162float(yp[tq]) : 0.f;
            v.y = (tq + 1 >= 0 && tq + 1 < NT) ? __bfloat162float(yp[tq + 1]) : 0.f;
            v.z = (tq + 2 >= 0 && tq + 2 < NT) ? __bfloat162float(yp[tq + 2]) : 0.f;
            v.w = (tq + 3 >= 0 && tq + 3 < NT) ? __bfloat162float(yp[tq + 3]) : 0.f;
        }
        yt4[w ^ ((w >> 3) & 1)] = v;
    }
    __syncthreads();
    const float* cf = c1w + (j >> 1) * 64; // wave-uniform -> scalar loads
    int u = u0 + threadIdx.x;
    if (u < 2000) {
        float acc[8];
        #pragma unroll
        for (int s = 0; s < 8; s++) acc[s] = 0.f;
        #pragma unroll
        for (int kb = 0; kb < 64; kb += 16) {
            int B0 = 2 * threadIdx.x + (kb >> 2);
            float Yb[24];
            #pragma unroll
            for (int q = 0; q < 6; q++) {
                int w = B0 + q;
                float4 v = yt4[w ^ ((w >> 3) & 1)];
                Yb[4 * q] = v.x; Yb[4 * q + 1] = v.y;
                Yb[4 * q + 2] = v.z; Yb[4 * q + 3] = v.w;
            }
            #pragma unroll
            for (int k = 0; k < 16; k++) {
                float c = cf[kb + k];
                #pragma unroll
                for (int s = 0; s < 8; s++) acc[s] += c * Yb[k + s];
            }
        }
        const float bn2 = BN_C * BN_C;
        float pv = 0.f;
        #pragma unroll
        for (int s = 0; s < 8; s++) {
            float z = bn2 * acc[s];
            pv += (z > 0.f) ? z : expm1f(z);
        }
        p[((size_t)(b * 32 + j)) * 2000 + u] = pv * 0.125f;
    }
}

// ---------------- stage2: 4 u2 per block ----------------
__global__ __launch_bounds__(256) void k_stage2(const float* __restrict__ p,
                                                const float* __restrict__ dw2,
                                                const float* __restrict__ pw,
                                                float* __restrict__ feat) {
    int u2b = blockIdx.x * 4, b = blockIdx.y, t = threadIdx.x;
    __shared__ float pt[32][48];
    __shared__ float dval[32][32];
    __shared__ float w2s[512];
    __shared__ float pws[1536];
    for (int i = t; i < 512; i += 256) w2s[i] = dw2[i];
    for (int i = t; i < 1536; i += 256) pws[i] = pw[i];
    int base = 8 * u2b - 8;
    for (int i = t; i < 32 * 47; i += 256) {
        int j = i / 47, tt = i % 47;
        int gt = base + tt;
        pt[j][tt] = (gt >= 0 && gt < 2000) ? p[((size_t)(b * 32 + j)) * 2000 + gt] : 0.f;
    }
    __syncthreads();
    for (int i = t; i < 1024; i += 256) {
        int j = i >> 5, su = i & 31;
        int u = su >> 3, s = su & 7;
        float a = 0.f;
        #pragma unroll
        for (int k = 0; k < 16; k++) a += w2s[j * 16 + k] * pt[j][8 * u + s + k];
        dval[j][su] = a * BN_C;
    }
    __syncthreads();
    if (t < 192) {
        int col = t % ND, u = t / ND;
        int u2 = u2b + u;
        if (u2 < 250) {
            float wreg[32];
            #pragma unroll
            for (int j = 0; j < 32; j++) wreg[j] = pws[col * 32 + j];
            float acc = 0.f;
            #pragma unroll
            for (int s = 0; s < 8; s++) {
                float e = 0.f;
                #pragma unroll
                for (int j = 0; j < 32; j++) e += wreg[j] * dval[j][u * 8 + s];
                e *= BN_C;
                acc += (e > 0.f) ? e : expm1f(e);
            }
            feat[((size_t)b * 250 + u2) * ND + col] = acc * 0.125f;
        }
    }
}

// ---------------- fuse ----------------
__global__ __launch_bounds__(256) void k_fuse(
    const float* __restrict__ feat, const float* __restrict__ rfeat,
    const float* __restrict__ tc1w, const float* __restrict__ tc1b,
    const float* __restrict__ tc2w, const float* __restrict__ tc2b,
    const float* __restrict__ fp, const float* __restrict__ pe,
    float* __restrict__ fused) {
    int b = blockIdx.y;
    int sub = threadIdx.x >> 6, lt = threadIdx.x & 63;
    int n = blockIdx.x * 4 + sub;
    bool valid = (n < NSEQ);
    __shared__ float row[4][ND];
    __shared__ float g1[4][24];
    if (valid) {
        if (n == 0) {
            if (lt < ND) row[sub][lt] = rfeat[b * ND + lt];
        } else {
            int u = n - 1;
            if (lt < 24) {
                int m = lt;
                float a = tc1b[m];
                #pragma unroll
                for (int k = 0; k < 3; k++) {
                    int uu = u + k - 1;
                    if (uu >= 0 && uu < 250) {
                        float f0 = feat[((size_t)b * 250 + uu) * ND + 2 * m];
                        float f1 = feat[((size_t)b * 250 + uu) * ND + 2 * m + 1];
                        a += tc1w[m * 6 + k] * f0 + tc1w[m * 6 + 3 + k] * f1;
                    }
                }
                float z = a * BN_C;
                g1[sub][m] = 0.5f * z * (1.f + erff(z * 0.70710678f));
            }
        }
    }
    __syncthreads();
    if (valid && n > 0 && lt < ND) {
        int u = n - 1;
        float a = tc2b[lt];
        #pragma unroll
        for (int m = 0; m < 24; m++) a += tc2w[lt * 24 + m] * g1[sub][m];
        row[sub][lt] = feat[((size_t)b * 250 + u) * ND + lt] + a;
    }
    __syncthreads();
    if (valid && lt < ND) {
        float o = pe[n * ND + lt];
        for (int c = 0; c < ND; c++) o += row[sub][c] * fp[c * ND + lt];
        fused[((size_t)b * NSEQ + n) * ND + lt] = o;
    }
}

// ---------------- Fused transformer layer: block 512 ----------------
__global__ __launch_bounds__(512) void k_layer(
    float* __restrict__ fused,
    const float* __restrict__ g1v, const float* __restrict__ b1v,
    const float* __restrict__ qw, const float* __restrict__ qb,
    const float* __restrict__ apw, const float* __restrict__ apb,
    const float* __restrict__ g2v, const float* __restrict__ b2v,
    const float* __restrict__ w1, const float* __restrict__ fb1,
    const float* __restrict__ w2, const float* __restrict__ fb2) {
    int tile = blockIdx.x, b = blockIdx.y;
    int n0 = tile * TR;
    int t = threadIdx.x;
    __shared__ float row[TE][ND];
    __shared__ float hh[TE][ND];
    __shared__ float qkvS[TE * 144];
    __shared__ float ob[TR][ND];
    __shared__ float nrow[TR][ND];
    __shared__ float mrs[TE][2];
    __shared__ float part[4][TR][ND];
    float* hid = qkvS;

    for (int i = t; i < TE * ND; i += 512) {
        int e = i / ND, c = i % ND;
        int n = n0 - 5 + e;
        row[e][c] = (n >= 0 && n < NSEQ) ? fused[((size_t)b * NSEQ + n) * ND + c] : 0.f;
    }
    __syncthreads();
    if (t < TE * 16) {
        int r = t >> 4, i = t & 15;
        float v0 = row[r][i], v1 = row[r][i + 16], v2 = row[r][i + 32];
        float s = v0 + v1 + v2;
        s += __shfl_down(s, 8, 16); s += __shfl_down(s, 4, 16);
        s += __shfl_down(s, 2, 16); s += __shfl_down(s, 1, 16);
        float m = __shfl(s, 0, 16) * (1.f / ND);
        float d0 = v0 - m, d1 = v1 - m, d2 = v2 - m;
        float q = d0 * d0 + d1 * d1 + d2 * d2;
        q += __shfl_down(q, 8, 16); q += __shfl_down(q, 4, 16);
        q += __shfl_down(q, 2, 16); q += __shfl_down(q, 1, 16);
        if (i == 0) { mrs[r][0] = m; mrs[r][1] = rsqrtf(q * (1.f / ND) + 1e-5f); }
    }
    __syncthreads();
    for (int i = t; i < TE * ND; i += 512) {
        int e = i / ND, c = i % ND;
        hh[e][c] = (row[e][c] - mrs[e][0]) * mrs[e][1] * g1v[c] + b1v[c];
    }
    __syncthreads();
    if (t < 288) {
        int col = t % 144, eg = t / 144;
        float w[ND];
        #pragma unroll
        for (int c = 0; c < ND; c++) w[c] = qw[c * 144 + col];
        float bias = qb[col];
        for (int e = eg * 9; e < eg * 9 + 9; e++) {
            float a = bias;
            #pragma unroll
            for (int c = 0; c < ND; c++) a += hh[e][c] * w[c];
            qkvS[e * 144 + col] = a;
        }
    }
    __syncthreads();
    if (t < TR * 8) {
        int r = t >> 3, h = t & 7;
        int n = n0 + r;
        if (n < NSEQ) {
            int k0 = n - 5; if (k0 < 0) k0 = 0;
            int k1 = n + 5; if (k1 > NSEQ - 1) k1 = NSEQ - 1;
            int nk = k1 - k0 + 1;
            float q[6];
            #pragma unroll
            for (int d = 0; d < 6; d++) q[d] = qkvS[(r + 5) * 144 + h * 6 + d];
            float sc[11];
            float mx = -1e30f;
            for (int ki = 0; ki < nk; ki++) {
                int e = k0 + ki - n0 + 5;
                float s = 0;
                #pragma unroll
                for (int d = 0; d < 6; d++) s += q[d] * qkvS[e * 144 + 48 + h * 6 + d];
                s *= 0.4082482904638631f;
                sc[ki] = s; mx = fmaxf(mx, s);
            }
            float sum = 0;
            for (int ki = 0; ki < nk; ki++) { float e = expf(sc[ki] - mx); sc[ki] = e; sum += e; }
            float inv = 1.f / sum;
            float o[6] = {0, 0, 0, 0, 0, 0};
            for (int ki = 0; ki < nk; ki++) {
                int e = k0 + ki - n0 + 5;
                float pv = sc[ki] * inv;
                #pragma unroll
                for (int d = 0; d < 6; d++) o[d] += pv * qkvS[e * 144 + 96 + h * 6 + d];
            }
            #pragma unroll
            for (int d = 0; d < 6; d++) ob[r][h * 6 + d] = o[d];
        } else {
            #pragma unroll
            for (int d = 0; d < 6; d++) ob[r][h * 6 + d] = 0.f;
        }
    }
    __syncthreads();
    if (t < TR * ND) {
        int r = t / ND, col = t % ND;
        float a = apb[col];
        #pragma unroll
        for (int c = 0; c < ND; c++) a += ob[r][c] * apw[c * ND + col];
        nrow[r][col] = row[r + 5][col] + a;
    }
    __syncthreads();
    if (t < TR * 16) {
        int r = t >> 4, i = t & 15;
        float v0 = nrow[r][i], v1 = nrow[r][i + 16], v2 = nrow[r][i + 32];
        float s = v0 + v1 + v2;
        s += __shfl_down(s, 8, 16); s += __shfl_down(s, 4, 16);
        s += __shfl_down(s, 2, 16); s += __shfl_down(s, 1, 16);
        float m = __shfl(s, 0, 16) * (1.f / ND);
        float d0 = v0 - m, d1 = v1 - m, d2 = v2 - m;
        float q = d0 * d0 + d1 * d1 + d2 * d2;
        q += __shfl_down(q, 8, 16); q += __shfl_down(q, 4, 16);
        q += __shfl_down(q, 2, 16); q += __shfl_down(q, 1, 16);
        if (i == 0) { mrs[r][0] = m; mrs[r][1] = rsqrtf(q * (1.f / ND) + 1e-5f); }
    }
    __syncthreads();
    if (t < TR * ND) {
        int r = t / ND, c = t % ND;
        hh[r][c] = (nrow[r][c] - mrs[r][0]) * mrs[r][1] * g2v[c] + b2v[c];
    }
    __syncthreads();
    if (t < 384) {
        int col = t % 192, rg = t / 192;
        float w[ND];
        #pragma unroll
        for (int c = 0; c < ND; c++) w[c] = w1[c * 192 + col];
        float bias = fb1[col];
        for (int r = rg * 4; r < rg * 4 + 4; r++) {
            float a = bias;
            #pragma unroll
            for (int c = 0; c < ND; c++) a += hh[r][c] * w[c];
            hid[r * 192 + col] = 0.5f * a * (1.f + erff(a * 0.70710678f));
        }
    }
    __syncthreads();
    if (t < 384) {
        int col = t % ND, kc = (t / ND) & 3, rh = t / 192;
        float w[ND];
        #pragma unroll
        for (int i2 = 0; i2 < ND; i2++) w[i2] = w2[(kc * ND + i2) * ND + col];
        for (int r = rh * 4; r < rh * 4 + 4; r++) {
            float a = 0;
            #pragma unroll
            for (int i2 = 0; i2 < ND; i2++) a += hid[r * 192 + kc * ND + i2] * w[i2];
            part[kc][r][col] = a;
        }
    }
    __syncthreads();
    for (int i = t; i < TR * ND; i += 512) {
        int r = i / ND, c = i % ND;
        int n = n0 + r;
        if (n < NSEQ) {
            fused[((size_t)b * NSEQ + n) * ND + c] =
                nrow[r][c] + fb2[c] + part[0][r][c] + part[1][r][c] + part[2][r][c] + part[3][r][c];
        }
    }
}

__global__ void k_head(const float* __restrict__ fused, const float* __restrict__ lg,
                       const float* __restrict__ lb, const float* __restrict__ cw,
                       const float* __restrict__ cb, float* __restrict__ out) {
    int b = blockIdx.x, t = threadIdx.x;
    __shared__ float part[4][ND];
    __shared__ float gg[ND], mv[2];
    if (t < 192) {
        int col = t % ND, qt = t / ND;
        int nA = qt * 63;
        int nB = (nA + 63 < NSEQ) ? nA + 63 : NSEQ;
        float s = 0.f;
        for (int n = nA; n < nB; n++) s += fused[((size_t)b * NSEQ + n) * ND + col];
        part[qt][col] = s;
    }
    __syncthreads();
    if (t < ND) gg[t] = (part[0][t] + part[1][t] + part[2][t] + part[3][t]) * (1.f / NSEQ);
    __syncthreads();
    if (t == 0) {
        float m = 0;
        for (int c = 0; c < ND; c++) m += gg[c];
        m /= (float)ND;
        float v = 0;
        for (int c = 0; c < ND; c++) { float dd = gg[c] - m; v += dd * dd; }
        v /= (float)ND;
        mv[0] = m; mv[1] = rsqrtf(v + 1e-5f);
    }
    __syncthreads();
    if (t < ND) gg[t] = (gg[t] - mv[0]) * mv[1] * lg[t] + lb[t];
    __syncthreads();
    if (t < 4) {
        float a = cb[t];
        for (int c = 0; c < ND; c++) a += gg[c] * cw[c * 4 + t];
        out[b * 4 + t] = a;
    }
}

extern "C" void kernel_launch(void* const* d_in, const int* in_sizes, int n_in,
                              void* d_out, int out_size, void* d_ws, size_t ws_size,
                              hipStream_t stream) {
    const float* x       = (const float*)d_in[0];
    const float* riem_w1 = (const float*)d_in[1];
    const float* riem_b1 = (const float*)d_in[2];
    const float* riem_w2 = (const float*)d_in[3];
    const float* riem_b2 = (const float*)d_in[4];
    const float* conv1_w = (const float*)d_in[5];
    const float* dw1_w   = (const float*)d_in[6];
    const float* dw2_w   = (const float*)d_in[7];
    const float* pw_w    = (const float*)d_in[8];
    const float* tc1_w   = (const float*)d_in[9];
    const float* tc1_b   = (const float*)d_in[10];
    const float* tc2_w   = (const float*)d_in[11];
    const float* tc2_b   = (const float*)d_in[12];
    const float* fusion  = (const float*)d_in[13];
    const float* pos_enc = (const float*)d_in[14];
    const float* ln1_g   = (const float*)d_in[15];
    const float* ln1_b   = (const float*)d_in[16];
    const float* qkv_w   = (const float*)d_in[17];
    const float* qkv_b   = (const float*)d_in[18];
    const float* apw     = (const float*)d_in[19];
    const float* apb     = (const float*)d_in[20];
    const float* ln2_g   = (const float*)d_in[21];
    const float* ln2_b   = (const float*)d_in[22];
    const float* ffn_w1  = (const float*)d_in[23];
    const float* ffn_b1  = (const float*)d_in[24];
    const float* ffn_w2  = (const float*)d_in[25];
    const float* ffn_b2  = (const float*)d_in[26];
    const float* cls_g   = (const float*)d_in[27];
    const float* cls_b_  = (const float*)d_in[28];
    const float* cls_w   = (const float*)d_in[29];
    const float* cls_bb  = (const float*)d_in[30];
    float* out = (float*)d_out;

    float* ws = (float*)d_ws;
    float* covS  = ws;                 // 4048
    float* sums  = ws + 4048;          // 352
    float* rfeat = ws + 4400;          // 768
    float* feat  = ws + 5168;          // 192000
    float* fused = ws + 197168;        // 192768
    float* pbuf  = ws + 389936;        // 1024000
    __hip_bfloat16* ybuf = (__hip_bfloat16*)(ws + 1413936); // 8192000 bf16

    hipMemsetAsync(covS, 0, 4400 * sizeof(float), stream);

    k_y<<<500, 256, 0, stream>>>(x, dw1_w, ybuf);
    k_covS<<<dim3(32, NB), 256, 0, stream>>>(x, covS, sums);
    k_cholfeat<<<NB, 256, 0, stream>>>(covS, sums, riem_w1, riem_b1, riem_w2, riem_b2, rfeat);

    k_conv64<<<dim3(8, 32, NB), 256, 0, stream>>>(ybuf, conv1_w, pbuf);
    k_stage2<<<dim3(63, NB), 256, 0, stream>>>(pbuf, dw2_w, pw_w, feat);
    k_fuse<<<dim3(63, NB), 256, 0, stream>>>(feat, rfeat, tc1_w, tc1_b, tc2_w, tc2_b,
                                             fusion, pos_enc, fused);

    for (int i = 0; i < 4; i++) {
        k_layer<<<dim3(32, NB), 512, 0, stream>>>(
            fused, ln1_g + i * 48, ln1_b + i * 48, qkv_w + i * 6912, qkv_b + i * 144,
            apw + i * 2304, apb + i * 48, ln2_g + i * 48, ln2_b + i * 48,
            ffn_w1 + i * 9216, ffn_b1 + i * 192, ffn_w2 + i * 9216, ffn_b2 + i * 48);
    }

    k_head<<<NB, 256, 0, stream>>>(fused, cls_g, cls_b_, cls_w, cls_bb, out);
}

// Round 12
// 273.505 us; speedup vs baseline: 1.1053x; 1.0557x over previous
//
#include <hip/hip_runtime.h>
#include <hip/hip_bf16.h>
#include <math.h>

#define BN_C 0.9999950000375f
#define NB 16
#define NC 22
#define NT 16000
#define NPAIR 253
#define NSEQ 251
#define ND 48
#define TR 8
#define TE 18

__device__ __forceinline__ unsigned short f2bf(float f) {
    union { float f; unsigned int u; } v; v.f = f;
    unsigned int r = v.u + 0x7fff + ((v.u >> 16) & 1);
    return (unsigned short)(r >> 16);
}
__device__ __forceinline__ float bf2f(unsigned short s) {
    union { unsigned int u; float f; } v; v.u = ((unsigned int)s) << 16;
    return v.f;
}
__device__ __forceinline__ float elu_fast(float z) {
    return (z > 0.f) ? z : (__expf(z) - 1.f);
}

// ---------------- merged y-production + cov sums: grid 1012, block 256 ----------------
// bx < 512: covS part (chunk = bx%32, b = bx/32); bx >= 512: y part.
#define TCHUNK 500
#define XROW 504
__global__ __launch_bounds__(256) void k_ycov(const float* __restrict__ x,
                                              const float* __restrict__ dw1,
                                              __hip_bfloat16* __restrict__ y,
                                              float* __restrict__ covS,
                                              float* __restrict__ sums) {
    __shared__ unsigned short xs[NC * XROW];
    if (blockIdx.x < 512) {
        int chunk = blockIdx.x & 31, b = blockIdx.x >> 5;
        int t0 = chunk * TCHUNK;
        const float* xp = x + (size_t)b * NC * NT + t0;
        for (int i = threadIdx.x; i < NC * 126; i += 256) {
            int c = i / 126, q = i % 126;
            unsigned long long pk = 0ull;
            if (q < 125) {
                float4 v = *(const float4*)&xp[(size_t)c * NT + 4 * q];
                pk = (unsigned long long)f2bf(v.x) | ((unsigned long long)f2bf(v.y) << 16)
                   | ((unsigned long long)f2bf(v.z) << 32) | ((unsigned long long)f2bf(v.w) << 48);
            }
            *(unsigned long long*)&xs[c * XROW + 4 * q] = pk;
        }
        __syncthreads();
        int p = threadIdx.x;
        if (p < NPAIR) {
            int c = 0, r = p;
            while (r >= NC - c) { r -= NC - c; c++; }
            int d = c + r;
            const unsigned short* xc = &xs[c * XROW];
            const unsigned short* xd = &xs[d * XROW];
            float a0 = 0, a1 = 0, a2 = 0, a3 = 0;
            float s0 = 0, s1 = 0, s2 = 0, s3 = 0;
            for (int t = 0; t < XROW; t += 8) {
                uint4 pc = *(const uint4*)&xc[t];
                uint4 pd = *(const uint4*)&xd[t];
                float c0 = bf2f((unsigned short)pc.x), c1 = bf2f((unsigned short)(pc.x >> 16));
                float c2 = bf2f((unsigned short)pc.y), c3 = bf2f((unsigned short)(pc.y >> 16));
                float c4 = bf2f((unsigned short)pc.z), c5 = bf2f((unsigned short)(pc.z >> 16));
                float c6 = bf2f((unsigned short)pc.w), c7 = bf2f((unsigned short)(pc.w >> 16));
                float d0 = bf2f((unsigned short)pd.x), d1 = bf2f((unsigned short)(pd.x >> 16));
                float d2 = bf2f((unsigned short)pd.y), d3 = bf2f((unsigned short)(pd.y >> 16));
                float d4 = bf2f((unsigned short)pd.z), d5 = bf2f((unsigned short)(pd.z >> 16));
                float d6 = bf2f((unsigned short)pd.w), d7 = bf2f((unsigned short)(pd.w >> 16));
                a0 += c0 * d0 + c4 * d4; a1 += c1 * d1 + c5 * d5;
                a2 += c2 * d2 + c6 * d6; a3 += c3 * d3 + c7 * d7;
                s0 += c0 + c4; s1 += c1 + c5; s2 += c2 + c6; s3 += c3 + c7;
            }
            atomicAdd(&covS[b * NPAIR + p], (a0 + a1) + (a2 + a3));
            if (c == d) atomicAdd(&sums[b * NC + c], (s0 + s1) + (s2 + s3));
        }
    } else {
        int gid = (blockIdx.x - 512) * 256 + threadIdx.x; // 128000
        int b = gid / 8000, tp = gid % 8000;
        int t = tp * 2;
        const float* xb = x + (size_t)b * NC * NT + t;
        float a0[32], a1[32];
        #pragma unroll
        for (int j = 0; j < 32; j++) { a0[j] = 0.f; a1[j] = 0.f; }
        for (int h = 0; h < NC; h++) {
            float2 xv = *(const float2*)&xb[(size_t)h * NT];
            #pragma unroll
            for (int j = 0; j < 32; j++) {
                float w = dw1[j * NC + h];
                a0[j] += w * xv.x; a1[j] += w * xv.y;
            }
        }
        unsigned int* yo = (unsigned int*)(y + (size_t)b * 32 * NT + t);
        #pragma unroll
        for (int j = 0; j < 32; j++) {
            unsigned int pk = (unsigned int)f2bf(a0[j]) | ((unsigned int)f2bf(a1[j]) << 16);
            yo[j * (NT / 2)] = pk;
        }
    }
}

// ---------------- merged conv64 + cholfeat: grid 4112, block 256 ----------------
__global__ __launch_bounds__(256) void k_convchol(
    const __hip_bfloat16* __restrict__ y, const float* __restrict__ c1w,
    float* __restrict__ p,
    const float* __restrict__ covS, const float* __restrict__ sums,
    const float* __restrict__ w1, const float* __restrict__ b1,
    const float* __restrict__ w2, const float* __restrict__ b2,
    float* __restrict__ rfeat) {
    __shared__ float4 yt4[528];
    __shared__ float covL[484];
    __shared__ float trS[NB];
    __shared__ float dvs[NC];
    __shared__ float hid[256];
    __shared__ float part[4][ND];
    if (blockIdx.x < 4096) {
        // ---- conv64 part ----
        int tile = blockIdx.x & 7, j = (blockIdx.x >> 3) & 31, b = blockIdx.x >> 8;
        int u0 = tile * 256;
        const __hip_bfloat16* yp = y + ((size_t)(b * 32 + j)) * NT;
        int tbase = u0 * 8 - 32;
        for (int w = threadIdx.x; w < 528; w += 256) {
            int tq = tbase + 4 * w;
            float4 v;
            if (tq >= 0 && tq + 3 < NT) {
                uint2 pk = *(const uint2*)(yp + tq);
                v.x = bf2f((unsigned short)pk.x); v.y = bf2f((unsigned short)(pk.x >> 16));
                v.z = bf2f((unsigned short)pk.y); v.w = bf2f((unsigned short)(pk.y >> 16));
            } else {
                v.x = (tq >= 0 && tq < NT) ? __bfloat162float(yp[tq]) : 0.f;
                v.y = (tq + 1 >= 0 && tq + 1 < NT) ? __bfloat162float(yp[tq + 1]) : 0.f;
                v.z = (tq + 2 >= 0 && tq + 2 < NT) ? __bfloat162float(yp[tq + 2]) : 0.f;
                v.w = (tq + 3 >= 0 && tq + 3 < NT) ? __bfloat162float(yp[tq + 3]) : 0.f;
            }
            yt4[w ^ ((w >> 3) & 1)] = v;
        }
        __syncthreads();
        const float* cf = c1w + (j >> 1) * 64;
        int u = u0 + threadIdx.x;
        if (u < 2000) {
            float acc[8];
            #pragma unroll
            for (int s = 0; s < 8; s++) acc[s] = 0.f;
            #pragma unroll
            for (int kb = 0; kb < 64; kb += 16) {
                int B0 = 2 * threadIdx.x + (kb >> 2);
                float Yb[24];
                #pragma unroll
                for (int q = 0; q < 6; q++) {
                    int w = B0 + q;
                    float4 v = yt4[w ^ ((w >> 3) & 1)];
                    Yb[4 * q] = v.x; Yb[4 * q + 1] = v.y;
                    Yb[4 * q + 2] = v.z; Yb[4 * q + 3] = v.w;
                }
                #pragma unroll
                for (int k = 0; k < 16; k++) {
                    float c = cf[kb + k];
                    #pragma unroll
                    for (int s = 0; s < 8; s++) acc[s] += c * Yb[k + s];
                }
            }
            const float bn2 = BN_C * BN_C;
            float pv = 0.f;
            #pragma unroll
            for (int s = 0; s < 8; s++) pv += elu_fast(bn2 * acc[s]);
            p[((size_t)(b * 32 + j)) * 2000 + u] = pv * 0.125f;
        }
    } else {
        // ---- cholfeat part ----
        int b = blockIdx.x - 4096, t = threadIdx.x;
        if (t < NB) trS[t] = 0.f;
        __syncthreads();
        if (t < NPAIR) {
            int c = 0, r = t;
            while (r >= NC - c) { r -= NC - c; c++; }
            int d = c + r;
            float v = (covS[b * NPAIR + t] - sums[b * NC + c] * sums[b * NC + d] / (float)NT)
                      / (float)(NT - 1);
            if (c == d) v += 1e-5f;
            covL[c * NC + d] = v;
            covL[d * NC + c] = v;
        }
        for (int i = t; i < NB * NC; i += 256) {
            int bb = i / NC, c = i % NC;
            int pos = c * NC - c * (c - 1) / 2;
            float sc = sums[bb * NC + c];
            float v = (covS[bb * NPAIR + pos] - sc * sc / (float)NT) / (float)(NT - 1) + 1e-5f;
            atomicAdd(&trS[bb], v);
        }
        __syncthreads();
        float trs = 0.f;
        for (int i = 0; i < NB; i++) trs += trS[i];
        float trm = trs * (0.001f / (float)NB);
        if (t < 64) {
            int lane = t;
            float a[NC];
            #pragma unroll
            for (int j = 0; j < NC; j++) {
                float v = (lane < NC) ? covL[lane * NC + j] : 0.f;
                a[j] = v + ((j == lane) ? trm : 0.f);
            }
            float diagv = 1.f;
            #pragma unroll
            for (int k = 0; k < NC; k++) {
                float akk = __shfl(a[k], k);
                float dk = sqrtf(akk);
                if (lane == k) { a[k] = dk; diagv = dk; }
                else if (lane > k) a[k] /= dk;
                float myak = a[k];
                #pragma unroll
                for (int j = k + 1; j < NC; j++) {
                    float ljk = __shfl(myak, j);
                    if (lane >= j) a[j] -= myak * ljk;
                }
            }
            if (lane < NC) dvs[lane] = diagv * logf(fmaxf(diagv, 1e-10f));
        }
        __syncthreads();
        {
            float acc = b1[t];
            #pragma unroll
            for (int d = 0; d < NC; d++) {
                int pos = d * NC - d * (d - 1) / 2;
                acc += dvs[d] * w1[pos * 256 + t];
            }
            hid[t] = elu_fast(acc);
        }
        __syncthreads();
        if (t < 192) {
            int col = t % ND, kc = t / ND;
            float a = 0.f;
            #pragma unroll
            for (int i = 0; i < 64; i++) a += hid[kc * 64 + i] * w2[(kc * 64 + i) * ND + col];
            part[kc][col] = a;
        }
        __syncthreads();
        if (t < ND)
            rfeat[b * ND + t] = b2[t] + part[0][t] + part[1][t] + part[2][t] + part[3][t];
    }
}

// ---------------- stage2: 4 u2 per block ----------------
__global__ __launch_bounds__(256) void k_stage2(const float* __restrict__ p,
                                                const float* __restrict__ dw2,
                                                const float* __restrict__ pw,
                                                float* __restrict__ feat) {
    int u2b = blockIdx.x * 4, b = blockIdx.y, t = threadIdx.x;
    __shared__ float pt[32][48];
    __shared__ float dval[32][32];
    __shared__ float w2s[512];
    __shared__ float pws[1536];
    for (int i = t; i < 512; i += 256) w2s[i] = dw2[i];
    for (int i = t; i < 1536; i += 256) pws[i] = pw[i];
    int base = 8 * u2b - 8;
    for (int i = t; i < 32 * 47; i += 256) {
        int j = i / 47, tt = i % 47;
        int gt = base + tt;
        pt[j][tt] = (gt >= 0 && gt < 2000) ? p[((size_t)(b * 32 + j)) * 2000 + gt] : 0.f;
    }
    __syncthreads();
    for (int i = t; i < 1024; i += 256) {
        int j = i >> 5, su = i & 31;
        int u = su >> 3, s = su & 7;
        float a = 0.f;
        #pragma unroll
        for (int k = 0; k < 16; k++) a += w2s[j * 16 + k] * pt[j][8 * u + s + k];
        dval[j][su] = a * BN_C;
    }
    __syncthreads();
    if (t < 192) {
        int col = t % ND, u = t / ND;
        int u2 = u2b + u;
        if (u2 < 250) {
            float wreg[32];
            #pragma unroll
            for (int j = 0; j < 32; j++) wreg[j] = pws[col * 32 + j];
            float acc = 0.f;
            #pragma unroll
            for (int s = 0; s < 8; s++) {
                float e = 0.f;
                #pragma unroll
                for (int j = 0; j < 32; j++) e += wreg[j] * dval[j][u * 8 + s];
                acc += elu_fast(e * BN_C);
            }
            feat[((size_t)b * 250 + u2) * ND + col] = acc * 0.125f;
        }
    }
}

// ---------------- fuse ----------------
__global__ __launch_bounds__(256) void k_fuse(
    const float* __restrict__ feat, const float* __restrict__ rfeat,
    const float* __restrict__ tc1w, const float* __restrict__ tc1b,
    const float* __restrict__ tc2w, const float* __restrict__ tc2b,
    const float* __restrict__ fp, const float* __restrict__ pe,
    float* __restrict__ fused) {
    int b = blockIdx.y;
    int sub = threadIdx.x >> 6, lt = threadIdx.x & 63;
    int n = blockIdx.x * 4 + sub;
    bool valid = (n < NSEQ);
    __shared__ float row[4][ND];
    __shared__ float g1[4][24];
    if (valid) {
        if (n == 0) {
            if (lt < ND) row[sub][lt] = rfeat[b * ND + lt];
        } else {
            int u = n - 1;
            if (lt < 24) {
                int m = lt;
                float a = tc1b[m];
                #pragma unroll
                for (int k = 0; k < 3; k++) {
                    int uu = u + k - 1;
                    if (uu >= 0 && uu < 250) {
                        float f0 = feat[((size_t)b * 250 + uu) * ND + 2 * m];
                        float f1 = feat[((size_t)b * 250 + uu) * ND + 2 * m + 1];
                        a += tc1w[m * 6 + k] * f0 + tc1w[m * 6 + 3 + k] * f1;
                    }
                }
                float z = a * BN_C;
                g1[sub][m] = 0.5f * z * (1.f + erff(z * 0.70710678f));
            }
        }
    }
    __syncthreads();
    if (valid && n > 0 && lt < ND) {
        int u = n - 1;
        float a = tc2b[lt];
        #pragma unroll
        for (int m = 0; m < 24; m++) a += tc2w[lt * 24 + m] * g1[sub][m];
        row[sub][lt] = feat[((size_t)b * 250 + u) * ND + lt] + a;
    }
    __syncthreads();
    if (valid && lt < ND) {
        float o = pe[n * ND + lt];
        for (int c = 0; c < ND; c++) o += row[sub][c] * fp[c * ND + lt];
        fused[((size_t)b * NSEQ + n) * ND + lt] = o;
    }
}

// ---------------- Fused transformer layer: block 512 ----------------
__global__ __launch_bounds__(512) void k_layer(
    float* __restrict__ fused,
    const float* __restrict__ g1v, const float* __restrict__ b1v,
    const float* __restrict__ qw, const float* __restrict__ qb,
    const float* __restrict__ apw, const float* __restrict__ apb,
    const float* __restrict__ g2v, const float* __restrict__ b2v,
    const float* __restrict__ w1, const float* __restrict__ fb1,
    const float* __restrict__ w2, const float* __restrict__ fb2) {
    int tile = blockIdx.x, b = blockIdx.y;
    int n0 = tile * TR;
    int t = threadIdx.x;
    __shared__ float row[TE][ND];
    __shared__ float hh[TE][ND];
    __shared__ float qkvS[TE * 144];
    __shared__ float ob[TR][ND];
    __shared__ float nrow[TR][ND];
    __shared__ float mrs[TE][2];
    __shared__ float part[4][TR][ND];
    float* hid = qkvS;

    for (int i = t; i < TE * ND; i += 512) {
        int e = i / ND, c = i % ND;
        int n = n0 - 5 + e;
        row[e][c] = (n >= 0 && n < NSEQ) ? fused[((size_t)b * NSEQ + n) * ND + c] : 0.f;
    }
    __syncthreads();
    if (t < TE * 16) {
        int r = t >> 4, i = t & 15;
        float v0 = row[r][i], v1 = row[r][i + 16], v2 = row[r][i + 32];
        float s = v0 + v1 + v2;
        s += __shfl_down(s, 8, 16); s += __shfl_down(s, 4, 16);
        s += __shfl_down(s, 2, 16); s += __shfl_down(s, 1, 16);
        float m = __shfl(s, 0, 16) * (1.f / ND);
        float d0 = v0 - m, d1 = v1 - m, d2 = v2 - m;
        float q = d0 * d0 + d1 * d1 + d2 * d2;
        q += __shfl_down(q, 8, 16); q += __shfl_down(q, 4, 16);
        q += __shfl_down(q, 2, 16); q += __shfl_down(q, 1, 16);
        if (i == 0) { mrs[r][0] = m; mrs[r][1] = rsqrtf(q * (1.f / ND) + 1e-5f); }
    }
    __syncthreads();
    for (int i = t; i < TE * ND; i += 512) {
        int e = i / ND, c = i % ND;
        hh[e][c] = (row[e][c] - mrs[e][0]) * mrs[e][1] * g1v[c] + b1v[c];
    }
    __syncthreads();
    if (t < 288) {
        int col = t % 144, eg = t / 144;
        float w[ND];
        #pragma unroll
        for (int c = 0; c < ND; c++) w[c] = qw[c * 144 + col];
        float bias = qb[col];
        for (int e = eg * 9; e < eg * 9 + 9; e++) {
            float a = bias;
            #pragma unroll
            for (int c = 0; c < ND; c++) a += hh[e][c] * w[c];
            qkvS[e * 144 + col] = a;
        }
    }
    __syncthreads();
    if (t < TR * 8) {
        int r = t >> 3, h = t & 7;
        int n = n0 + r;
        if (n < NSEQ) {
            int k0 = n - 5; if (k0 < 0) k0 = 0;
            int k1 = n + 5; if (k1 > NSEQ - 1) k1 = NSEQ - 1;
            int nk = k1 - k0 + 1;
            float q[6];
            #pragma unroll
            for (int d = 0; d < 6; d++) q[d] = qkvS[(r + 5) * 144 + h * 6 + d];
            float sc[11];
            float mx = -1e30f;
            for (int ki = 0; ki < nk; ki++) {
                int e = k0 + ki - n0 + 5;
                float s = 0;
                #pragma unroll
                for (int d = 0; d < 6; d++) s += q[d] * qkvS[e * 144 + 48 + h * 6 + d];
                s *= 0.4082482904638631f;
                sc[ki] = s; mx = fmaxf(mx, s);
            }
            float sum = 0;
            for (int ki = 0; ki < nk; ki++) { float e = __expf(sc[ki] - mx); sc[ki] = e; sum += e; }
            float inv = 1.f / sum;
            float o[6] = {0, 0, 0, 0, 0, 0};
            for (int ki = 0; ki < nk; ki++) {
                int e = k0 + ki - n0 + 5;
                float pv = sc[ki] * inv;
                #pragma unroll
                for (int d = 0; d < 6; d++) o[d] += pv * qkvS[e * 144 + 96 + h * 6 + d];
            }
            #pragma unroll
            for (int d = 0; d < 6; d++) ob[r][h * 6 + d] = o[d];
        } else {
            #pragma unroll
            for (int d = 0; d < 6; d++) ob[r][h * 6 + d] = 0.f;
        }
    }
    __syncthreads();
    if (t < TR * ND) {
        int r = t / ND, col = t % ND;
        float a = apb[col];
        #pragma unroll
        for (int c = 0; c < ND; c++) a += ob[r][c] * apw[c * ND + col];
        nrow[r][col] = row[r + 5][col] + a;
    }
    __syncthreads();
    if (t < TR * 16) {
        int r = t >> 4, i = t & 15;
        float v0 = nrow[r][i], v1 = nrow[r][i + 16], v2 = nrow[r][i + 32];
        float s = v0 + v1 + v2;
        s += __shfl_down(s, 8, 16); s += __shfl_down(s, 4, 16);
        s += __shfl_down(s, 2, 16); s += __shfl_down(s, 1, 16);
        float m = __shfl(s, 0, 16) * (1.f / ND);
        float d0 = v0 - m, d1 = v1 - m, d2 = v2 - m;
        float q = d0 * d0 + d1 * d1 + d2 * d2;
        q += __shfl_down(q, 8, 16); q += __shfl_down(q, 4, 16);
        q += __shfl_down(q, 2, 16); q += __shfl_down(q, 1, 16);
        if (i == 0) { mrs[r][0] = m; mrs[r][1] = rsqrtf(q * (1.f / ND) + 1e-5f); }
    }
    __syncthreads();
    if (t < TR * ND) {
        int r = t / ND, c = t % ND;
        hh[r][c] = (nrow[r][c] - mrs[r][0]) * mrs[r][1] * g2v[c] + b2v[c];
    }
    __syncthreads();
    if (t < 384) {
        int col = t % 192, rg = t / 192;
        float w[ND];
        #pragma unroll
        for (int c = 0; c < ND; c++) w[c] = w1[c * 192 + col];
        float bias = fb1[col];
        for (int r = rg * 4; r < rg * 4 + 4; r++) {
            float a = bias;
            #pragma unroll
            for (int c = 0; c < ND; c++) a += hh[r][c] * w[c];
            hid[r * 192 + col] = 0.5f * a * (1.f + erff(a * 0.70710678f));
        }
    }
    __syncthreads();
    if (t < 384) {
        int col = t % ND, kc = (t / ND) & 3, rh = t / 192;
        float w[ND];
        #pragma unroll
        for (int i2 = 0; i2 < ND; i2++) w[i2] = w2[(kc * ND + i2) * ND + col];
        for (int r = rh * 4; r < rh * 4 + 4; r++) {
            float a = 0;
            #pragma unroll
            for (int i2 = 0; i2 < ND; i2++) a += hid[r * 192 + kc * ND + i2] * w[i2];
            part[kc][r][col] = a;
        }
    }
    __syncthreads();
    for (int i = t; i < TR * ND; i += 512) {
        int r = i / ND, c = i % ND;
        int n = n0 + r;
        if (n < NSEQ) {
            fused[((size_t)b * NSEQ + n) * ND + c] =
                nrow[r][c] + fb2[c] + part[0][r][c] + part[1][r][c] + part[2][r][c] + part[3][r][c];
        }
    }
}

__global__ void k_head(const float* __restrict__ fused, const float* __restrict__ lg,
                       const float* __restrict__ lb, const float* __restrict__ cw,
                       const float* __restrict__ cb, float* __restrict__ out) {
    int b = blockIdx.x, t = threadIdx.x;
    __shared__ float part[4][ND];
    __shared__ float gg[ND], mv[2];
    if (t < 192) {
        int col = t % ND, qt = t / ND;
        int nA = qt * 63;
        int nB = (nA + 63 < NSEQ) ? nA + 63 : NSEQ;
        float s = 0.f;
        for (int n = nA; n < nB; n++) s += fused[((size_t)b * NSEQ + n) * ND + col];
        part[qt][col] = s;
    }
    __syncthreads();
    if (t < ND) gg[t] = (part[0][t] + part[1][t] + part[2][t] + part[3][t]) * (1.f / NSEQ);
    __syncthreads();
    if (t == 0) {
        float m = 0;
        for (int c = 0; c < ND; c++) m += gg[c];
        m /= (float)ND;
        float v = 0;
        for (int c = 0; c < ND; c++) { float dd = gg[c] - m; v += dd * dd; }
        v /= (float)ND;
        mv[0] = m; mv[1] = rsqrtf(v + 1e-5f);
    }
    __syncthreads();
    if (t < ND) gg[t] = (gg[t] - mv[0]) * mv[1] * lg[t] + lb[t];
    __syncthreads();
    if (t < 4) {
        float a = cb[t];
        for (int c = 0; c < ND; c++) a += gg[c] * cw[c * 4 + t];
        out[b * 4 + t] = a;
    }
}

extern "C" void kernel_launch(void* const* d_in, const int* in_sizes, int n_in,
                              void* d_out, int out_size, void* d_ws, size_t ws_size,
                              hipStream_t stream) {
    const float* x       = (const float*)d_in[0];
    const float* riem_w1 = (const float*)d_in[1];
    const float* riem_b1 = (const float*)d_in[2];
    const float* riem_w2 = (const float*)d_in[3];
    const float* riem_b2 = (const float*)d_in[4];
    const float* conv1_w = (const float*)d_in[5];
    const float* dw1_w   = (const float*)d_in[6];
    const float* dw2_w   = (const float*)d_in[7];
    const float* pw_w    = (const float*)d_in[8];
    const float* tc1_w   = (const float*)d_in[9];
    const float* tc1_b   = (const float*)d_in[10];
    const float* tc2_w   = (const float*)d_in[11];
    const float* tc2_b   = (const float*)d_in[12];
    const float* fusion  = (const float*)d_in[13];
    const float* pos_enc = (const float*)d_in[14];
    const float* ln1_g   = (const float*)d_in[15];
    const float* ln1_b   = (const float*)d_in[16];
    const float* qkv_w   = (const float*)d_in[17];
    const float* qkv_b   = (const float*)d_in[18];
    const float* apw     = (const float*)d_in[19];
    const float* apb     = (const float*)d_in[20];
    const float* ln2_g   = (const float*)d_in[21];
    const float* ln2_b   = (const float*)d_in[22];
    const float* ffn_w1  = (const float*)d_in[23];
    const float* ffn_b1  = (const float*)d_in[24];
    const float* ffn_w2  = (const float*)d_in[25];
    const float* ffn_b2  = (const float*)d_in[26];
    const float* cls_g   = (const float*)d_in[27];
    const float* cls_b_  = (const float*)d_in[28];
    const float* cls_w   = (const float*)d_in[29];
    const float* cls_bb  = (const float*)d_in[30];
    float* out = (float*)d_out;

    float* ws = (float*)d_ws;
    float* covS  = ws;                 // 4048
    float* sums  = ws + 4048;          // 352
    float* rfeat = ws + 4400;          // 768
    float* feat  = ws + 5168;          // 192000
    float* fused = ws + 197168;        // 192768
    float* pbuf  = ws + 389936;        // 1024000
    __hip_bfloat16* ybuf = (__hip_bfloat16*)(ws + 1413936); // 8192000 bf16

    hipMemsetAsync(covS, 0, 4400 * sizeof(float), stream);

    k_ycov<<<1012, 256, 0, stream>>>(x, dw1_w, ybuf, covS, sums);
    k_convchol<<<4112, 256, 0, stream>>>(ybuf, conv1_w, pbuf, covS, sums,
                                         riem_w1, riem_b1, riem_w2, riem_b2, rfeat);
    k_stage2<<<dim3(63, NB), 256, 0, stream>>>(pbuf, dw2_w, pw_w, feat);
    k_fuse<<<dim3(63, NB), 256, 0, stream>>>(feat, rfeat, tc1_w, tc1_b, tc2_w, tc2_b,
                                             fusion, pos_enc, fused);

    for (int i = 0; i < 4; i++) {
        k_layer<<<dim3(32, NB), 512, 0, stream>>>(
            fused, ln1_g + i * 48, ln1_b + i * 48, qkv_w + i * 6912, qkv_b + i * 144,
            apw + i * 2304, apb + i * 48, ln2_g + i * 48, ln2_b + i * 48,
            ffn_w1 + i * 9216, ffn_b1 + i * 192, ffn_w2 + i * 9216, ffn_b2 + i * 48);
    }

    k_head<<<NB, 256, 0, stream>>>(fused, cls_g, cls_b_, cls_w, cls_bb, out);
}

// Round 13
// 262.765 us; speedup vs baseline: 1.1505x; 1.0409x over previous
//
#include <hip/hip_runtime.h>
#include <hip/hip_bf16.h>
#include <math.h>

#define BN_C 0.9999950000375f
#define NB 16
#define NC 22
#define NT 16000
#define NPAIR 253
#define NSEQ 251
#define ND 48
#define TR 8
#define TE 18

__device__ __forceinline__ unsigned short f2bf(float f) {
    union { float f; unsigned int u; } v; v.f = f;
    unsigned int r = v.u + 0x7fff + ((v.u >> 16) & 1);
    return (unsigned short)(r >> 16);
}
__device__ __forceinline__ float bf2f(unsigned short s) {
    union { unsigned int u; float f; } v; v.u = ((unsigned int)s) << 16;
    return v.f;
}
__device__ __forceinline__ float elu_fast(float z) {
    return (z > 0.f) ? z : (__expf(z) - 1.f);
}

// ---------------- merged y-production + cov sums: grid 1012, block 256 ----------------
#define TCHUNK 500
#define XROW 504
__global__ __launch_bounds__(256) void k_ycov(const float* __restrict__ x,
                                              const float* __restrict__ dw1,
                                              __hip_bfloat16* __restrict__ y,
                                              float* __restrict__ covS,
                                              float* __restrict__ sums) {
    __shared__ unsigned short xs[NC * XROW];
    if (blockIdx.x < 512) {
        int chunk = blockIdx.x & 31, b = blockIdx.x >> 5;
        int t0 = chunk * TCHUNK;
        const float* xp = x + (size_t)b * NC * NT + t0;
        for (int i = threadIdx.x; i < NC * 126; i += 256) {
            int c = i / 126, q = i % 126;
            unsigned long long pk = 0ull;
            if (q < 125) {
                float4 v = *(const float4*)&xp[(size_t)c * NT + 4 * q];
                pk = (unsigned long long)f2bf(v.x) | ((unsigned long long)f2bf(v.y) << 16)
                   | ((unsigned long long)f2bf(v.z) << 32) | ((unsigned long long)f2bf(v.w) << 48);
            }
            *(unsigned long long*)&xs[c * XROW + 4 * q] = pk;
        }
        __syncthreads();
        int p = threadIdx.x;
        if (p < NPAIR) {
            int c = 0, r = p;
            while (r >= NC - c) { r -= NC - c; c++; }
            int d = c + r;
            const unsigned short* xc = &xs[c * XROW];
            const unsigned short* xd = &xs[d * XROW];
            float a0 = 0, a1 = 0, a2 = 0, a3 = 0;
            float s0 = 0, s1 = 0, s2 = 0, s3 = 0;
            for (int t = 0; t < XROW; t += 8) {
                uint4 pc = *(const uint4*)&xc[t];
                uint4 pd = *(const uint4*)&xd[t];
                float c0 = bf2f((unsigned short)pc.x), c1 = bf2f((unsigned short)(pc.x >> 16));
                float c2 = bf2f((unsigned short)pc.y), c3 = bf2f((unsigned short)(pc.y >> 16));
                float c4 = bf2f((unsigned short)pc.z), c5 = bf2f((unsigned short)(pc.z >> 16));
                float c6 = bf2f((unsigned short)pc.w), c7 = bf2f((unsigned short)(pc.w >> 16));
                float d0 = bf2f((unsigned short)pd.x), d1 = bf2f((unsigned short)(pd.x >> 16));
                float d2 = bf2f((unsigned short)pd.y), d3 = bf2f((unsigned short)(pd.y >> 16));
                float d4 = bf2f((unsigned short)pd.z), d5 = bf2f((unsigned short)(pd.z >> 16));
                float d6 = bf2f((unsigned short)pd.w), d7 = bf2f((unsigned short)(pd.w >> 16));
                a0 += c0 * d0 + c4 * d4; a1 += c1 * d1 + c5 * d5;
                a2 += c2 * d2 + c6 * d6; a3 += c3 * d3 + c7 * d7;
                s0 += c0 + c4; s1 += c1 + c5; s2 += c2 + c6; s3 += c3 + c7;
            }
            atomicAdd(&covS[b * NPAIR + p], (a0 + a1) + (a2 + a3));
            if (c == d) atomicAdd(&sums[b * NC + c], (s0 + s1) + (s2 + s3));
        }
    } else {
        int gid = (blockIdx.x - 512) * 256 + threadIdx.x; // 128000
        int b = gid / 8000, tp = gid % 8000;
        int t = tp * 2;
        const float* xb = x + (size_t)b * NC * NT + t;
        float a0[32], a1[32];
        #pragma unroll
        for (int j = 0; j < 32; j++) { a0[j] = 0.f; a1[j] = 0.f; }
        for (int h = 0; h < NC; h++) {
            float2 xv = *(const float2*)&xb[(size_t)h * NT];
            #pragma unroll
            for (int j = 0; j < 32; j++) {
                float w = dw1[j * NC + h];
                a0[j] += w * xv.x; a1[j] += w * xv.y;
            }
        }
        unsigned int* yo = (unsigned int*)(y + (size_t)b * 32 * NT + t);
        #pragma unroll
        for (int j = 0; j < 32; j++) {
            unsigned int pk = (unsigned int)f2bf(a0[j]) | ((unsigned int)f2bf(a1[j]) << 16);
            yo[j * (NT / 2)] = pk;
        }
    }
}

// ---------------- merged cholfeat (blocks 0-15) + conv64 (blocks 16-4111) ----------------
__global__ __launch_bounds__(256) void k_convchol(
    const __hip_bfloat16* __restrict__ y, const float* __restrict__ c1w,
    float* __restrict__ p,
    const float* __restrict__ covS, const float* __restrict__ sums,
    const float* __restrict__ w1, const float* __restrict__ b1,
    const float* __restrict__ w2, const float* __restrict__ b2,
    float* __restrict__ rfeat) {
    __shared__ float yt[2376];   // conv: padded fp32 window
    __shared__ float covL[484];
    __shared__ float trS[NB];
    __shared__ float dvs[NC];
    __shared__ float hid[256];
    __shared__ float part[4][ND];
    if (blockIdx.x >= NB) {
        // ---- conv64 part: padded scalar LDS (round-5 proven) ----
        int bx = blockIdx.x - NB;
        int tile = bx & 7, j = (bx >> 3) & 31, b = bx >> 8;
        int u0 = tile * 256;
        const __hip_bfloat16* yp = y + ((size_t)(b * 32 + j)) * NT;
        int tbase = u0 * 8 - 32;
        for (int q = threadIdx.x; q < 1056; q += 256) {
            int i = 2 * q;
            int tq = tbase + i;
            float v0 = 0.f, v1 = 0.f;
            if (tq >= 0 && tq + 1 < NT) {
                unsigned int pk = *(const unsigned int*)(yp + tq);
                v0 = bf2f((unsigned short)pk); v1 = bf2f((unsigned short)(pk >> 16));
            } else {
                if (tq >= 0 && tq < NT) v0 = __bfloat162float(yp[tq]);
                if (tq + 1 >= 0 && tq + 1 < NT) v1 = __bfloat162float(yp[tq + 1]);
            }
            yt[i + (i >> 3)] = v0;
            int i1 = i + 1;
            yt[i1 + (i1 >> 3)] = v1;
        }
        __syncthreads();
        const float* cf = c1w + (j >> 1) * 64; // wave-uniform -> scalar loads
        int u = u0 + threadIdx.x;
        if (u < 2000) {
            int off = 8 * threadIdx.x;
            float acc[8];
            #pragma unroll
            for (int s = 0; s < 8; s++) acc[s] = 0.f;
            #pragma unroll
            for (int kb = 0; kb < 64; kb += 16) {
                float Yb[23];
                #pragma unroll
                for (int m = 0; m < 23; m++) {
                    int idx = off + kb + m;
                    Yb[m] = yt[idx + (idx >> 3)];
                }
                #pragma unroll
                for (int k = 0; k < 16; k++) {
                    float c = cf[kb + k];
                    #pragma unroll
                    for (int s = 0; s < 8; s++) acc[s] += c * Yb[k + s];
                }
            }
            const float bn2 = BN_C * BN_C;
            float pv = 0.f;
            #pragma unroll
            for (int s = 0; s < 8; s++) pv += elu_fast(bn2 * acc[s]);
            p[((size_t)(b * 32 + j)) * 2000 + u] = pv * 0.125f;
        }
    } else {
        // ---- cholfeat part (blocks 0-15, scheduled first) ----
        int b = blockIdx.x, t = threadIdx.x;
        if (t < NB) trS[t] = 0.f;
        __syncthreads();
        if (t < NPAIR) {
            int c = 0, r = t;
            while (r >= NC - c) { r -= NC - c; c++; }
            int d = c + r;
            float v = (covS[b * NPAIR + t] - sums[b * NC + c] * sums[b * NC + d] / (float)NT)
                      / (float)(NT - 1);
            if (c == d) v += 1e-5f;
            covL[c * NC + d] = v;
            covL[d * NC + c] = v;
        }
        for (int i = t; i < NB * NC; i += 256) {
            int bb = i / NC, c = i % NC;
            int pos = c * NC - c * (c - 1) / 2;
            float sc = sums[bb * NC + c];
            float v = (covS[bb * NPAIR + pos] - sc * sc / (float)NT) / (float)(NT - 1) + 1e-5f;
            atomicAdd(&trS[bb], v);
        }
        __syncthreads();
        float trs = 0.f;
        for (int i = 0; i < NB; i++) trs += trS[i];
        float trm = trs * (0.001f / (float)NB);
        if (t < 64) {
            int lane = t;
            float a[NC];
            #pragma unroll
            for (int j = 0; j < NC; j++) {
                float v = (lane < NC) ? covL[lane * NC + j] : 0.f;
                a[j] = v + ((j == lane) ? trm : 0.f);
            }
            float diagv = 1.f;
            #pragma unroll
            for (int k = 0; k < NC; k++) {
                float akk = __shfl(a[k], k);
                float dk = sqrtf(akk);
                if (lane == k) { a[k] = dk; diagv = dk; }
                else if (lane > k) a[k] /= dk;
                float myak = a[k];
                #pragma unroll
                for (int j = k + 1; j < NC; j++) {
                    float ljk = __shfl(myak, j);
                    if (lane >= j) a[j] -= myak * ljk;
                }
            }
            if (lane < NC) dvs[lane] = diagv * logf(fmaxf(diagv, 1e-10f));
        }
        __syncthreads();
        {
            float acc = b1[t];
            #pragma unroll
            for (int d = 0; d < NC; d++) {
                int pos = d * NC - d * (d - 1) / 2;
                acc += dvs[d] * w1[pos * 256 + t];
            }
            hid[t] = elu_fast(acc);
        }
        __syncthreads();
        if (t < 192) {
            int col = t % ND, kc = t / ND;
            float a = 0.f;
            #pragma unroll
            for (int i = 0; i < 64; i++) a += hid[kc * 64 + i] * w2[(kc * 64 + i) * ND + col];
            part[kc][col] = a;
        }
        __syncthreads();
        if (t < ND)
            rfeat[b * ND + t] = b2[t] + part[0][t] + part[1][t] + part[2][t] + part[3][t];
    }
}

// ---------------- stage2: 4 u2 per block ----------------
__global__ __launch_bounds__(256) void k_stage2(const float* __restrict__ p,
                                                const float* __restrict__ dw2,
                                                const float* __restrict__ pw,
                                                float* __restrict__ feat) {
    int u2b = blockIdx.x * 4, b = blockIdx.y, t = threadIdx.x;
    __shared__ float pt[32][48];
    __shared__ float dval[32][32];
    __shared__ float w2s[512];
    __shared__ float pws[1536];
    for (int i = t; i < 512; i += 256) w2s[i] = dw2[i];
    for (int i = t; i < 1536; i += 256) pws[i] = pw[i];
    int base = 8 * u2b - 8;
    for (int i = t; i < 32 * 47; i += 256) {
        int j = i / 47, tt = i % 47;
        int gt = base + tt;
        pt[j][tt] = (gt >= 0 && gt < 2000) ? p[((size_t)(b * 32 + j)) * 2000 + gt] : 0.f;
    }
    __syncthreads();
    for (int i = t; i < 1024; i += 256) {
        int j = i >> 5, su = i & 31;
        int u = su >> 3, s = su & 7;
        float a = 0.f;
        #pragma unroll
        for (int k = 0; k < 16; k++) a += w2s[j * 16 + k] * pt[j][8 * u + s + k];
        dval[j][su] = a * BN_C;
    }
    __syncthreads();
    if (t < 192) {
        int col = t % ND, u = t / ND;
        int u2 = u2b + u;
        if (u2 < 250) {
            float wreg[32];
            #pragma unroll
            for (int j = 0; j < 32; j++) wreg[j] = pws[col * 32 + j];
            float acc = 0.f;
            #pragma unroll
            for (int s = 0; s < 8; s++) {
                float e = 0.f;
                #pragma unroll
                for (int j = 0; j < 32; j++) e += wreg[j] * dval[j][u * 8 + s];
                acc += elu_fast(e * BN_C);
            }
            feat[((size_t)b * 250 + u2) * ND + col] = acc * 0.125f;
        }
    }
}

// ---------------- fuse ----------------
__global__ __launch_bounds__(256) void k_fuse(
    const float* __restrict__ feat, const float* __restrict__ rfeat,
    const float* __restrict__ tc1w, const float* __restrict__ tc1b,
    const float* __restrict__ tc2w, const float* __restrict__ tc2b,
    const float* __restrict__ fp, const float* __restrict__ pe,
    float* __restrict__ fused) {
    int b = blockIdx.y;
    int sub = threadIdx.x >> 6, lt = threadIdx.x & 63;
    int n = blockIdx.x * 4 + sub;
    bool valid = (n < NSEQ);
    __shared__ float row[4][ND];
    __shared__ float g1[4][24];
    if (valid) {
        if (n == 0) {
            if (lt < ND) row[sub][lt] = rfeat[b * ND + lt];
        } else {
            int u = n - 1;
            if (lt < 24) {
                int m = lt;
                float a = tc1b[m];
                #pragma unroll
                for (int k = 0; k < 3; k++) {
                    int uu = u + k - 1;
                    if (uu >= 0 && uu < 250) {
                        float f0 = feat[((size_t)b * 250 + uu) * ND + 2 * m];
                        float f1 = feat[((size_t)b * 250 + uu) * ND + 2 * m + 1];
                        a += tc1w[m * 6 + k] * f0 + tc1w[m * 6 + 3 + k] * f1;
                    }
                }
                float z = a * BN_C;
                g1[sub][m] = 0.5f * z * (1.f + erff(z * 0.70710678f));
            }
        }
    }
    __syncthreads();
    if (valid && n > 0 && lt < ND) {
        int u = n - 1;
        float a = tc2b[lt];
        #pragma unroll
        for (int m = 0; m < 24; m++) a += tc2w[lt * 24 + m] * g1[sub][m];
        row[sub][lt] = feat[((size_t)b * 250 + u) * ND + lt] + a;
    }
    __syncthreads();
    if (valid && lt < ND) {
        float o = pe[n * ND + lt];
        for (int c = 0; c < ND; c++) o += row[sub][c] * fp[c * ND + lt];
        fused[((size_t)b * NSEQ + n) * ND + lt] = o;
    }
}

// ---------------- Fused transformer layer: block 512 ----------------
__global__ __launch_bounds__(512) void k_layer(
    float* __restrict__ fused,
    const float* __restrict__ g1v, const float* __restrict__ b1v,
    const float* __restrict__ qw, const float* __restrict__ qb,
    const float* __restrict__ apw, const float* __restrict__ apb,
    const float* __restrict__ g2v, const float* __restrict__ b2v,
    const float* __restrict__ w1, const float* __restrict__ fb1,
    const float* __restrict__ w2, const float* __restrict__ fb2) {
    int tile = blockIdx.x, b = blockIdx.y;
    int n0 = tile * TR;
    int t = threadIdx.x;
    __shared__ float row[TE][ND];
    __shared__ float hh[TE][ND];
    __shared__ float qkvS[TE * 144];
    __shared__ float ob[TR][ND];
    __shared__ float nrow[TR][ND];
    __shared__ float mrs[TE][2];
    __shared__ float part[4][TR][ND];
    float* hid = qkvS;

    for (int i = t; i < TE * ND; i += 512) {
        int e = i / ND, c = i % ND;
        int n = n0 - 5 + e;
        row[e][c] = (n >= 0 && n < NSEQ) ? fused[((size_t)b * NSEQ + n) * ND + c] : 0.f;
    }
    __syncthreads();
    if (t < TE * 16) {
        int r = t >> 4, i = t & 15;
        float v0 = row[r][i], v1 = row[r][i + 16], v2 = row[r][i + 32];
        float s = v0 + v1 + v2;
        s += __shfl_down(s, 8, 16); s += __shfl_down(s, 4, 16);
        s += __shfl_down(s, 2, 16); s += __shfl_down(s, 1, 16);
        float m = __shfl(s, 0, 16) * (1.f / ND);
        float d0 = v0 - m, d1 = v1 - m, d2 = v2 - m;
        float q = d0 * d0 + d1 * d1 + d2 * d2;
        q += __shfl_down(q, 8, 16); q += __shfl_down(q, 4, 16);
        q += __shfl_down(q, 2, 16); q += __shfl_down(q, 1, 16);
        if (i == 0) { mrs[r][0] = m; mrs[r][1] = rsqrtf(q * (1.f / ND) + 1e-5f); }
    }
    __syncthreads();
    for (int i = t; i < TE * ND; i += 512) {
        int e = i / ND, c = i % ND;
        hh[e][c] = (row[e][c] - mrs[e][0]) * mrs[e][1] * g1v[c] + b1v[c];
    }
    __syncthreads();
    if (t < 288) {
        int col = t % 144, eg = t / 144;
        float w[ND];
        #pragma unroll
        for (int c = 0; c < ND; c++) w[c] = qw[c * 144 + col];
        float bias = qb[col];
        for (int e = eg * 9; e < eg * 9 + 9; e++) {
            float a = bias;
            #pragma unroll
            for (int c = 0; c < ND; c++) a += hh[e][c] * w[c];
            qkvS[e * 144 + col] = a;
        }
    }
    __syncthreads();
    if (t < TR * 8) {
        int r = t >> 3, h = t & 7;
        int n = n0 + r;
        if (n < NSEQ) {
            int k0 = n - 5; if (k0 < 0) k0 = 0;
            int k1 = n + 5; if (k1 > NSEQ - 1) k1 = NSEQ - 1;
            int nk = k1 - k0 + 1;
            float q[6];
            #pragma unroll
            for (int d = 0; d < 6; d++) q[d] = qkvS[(r + 5) * 144 + h * 6 + d];
            float sc[11];
            float mx = -1e30f;
            for (int ki = 0; ki < nk; ki++) {
                int e = k0 + ki - n0 + 5;
                float s = 0;
                #pragma unroll
                for (int d = 0; d < 6; d++) s += q[d] * qkvS[e * 144 + 48 + h * 6 + d];
                s *= 0.4082482904638631f;
                sc[ki] = s; mx = fmaxf(mx, s);
            }
            float sum = 0;
            for (int ki = 0; ki < nk; ki++) { float e = __expf(sc[ki] - mx); sc[ki] = e; sum += e; }
            float inv = 1.f / sum;
            float o[6] = {0, 0, 0, 0, 0, 0};
            for (int ki = 0; ki < nk; ki++) {
                int e = k0 + ki - n0 + 5;
                float pv = sc[ki] * inv;
                #pragma unroll
                for (int d = 0; d < 6; d++) o[d] += pv * qkvS[e * 144 + 96 + h * 6 + d];
            }
            #pragma unroll
            for (int d = 0; d < 6; d++) ob[r][h * 6 + d] = o[d];
        } else {
            #pragma unroll
            for (int d = 0; d < 6; d++) ob[r][h * 6 + d] = 0.f;
        }
    }
    __syncthreads();
    if (t < TR * ND) {
        int r = t / ND, col = t % ND;
        float a = apb[col];
        #pragma unroll
        for (int c = 0; c < ND; c++) a += ob[r][c] * apw[c * ND + col];
        nrow[r][col] = row[r + 5][col] + a;
    }
    __syncthreads();
    if (t < TR * 16) {
        int r = t >> 4, i = t & 15;
        float v0 = nrow[r][i], v1 = nrow[r][i + 16], v2 = nrow[r][i + 32];
        float s = v0 + v1 + v2;
        s += __shfl_down(s, 8, 16); s += __shfl_down(s, 4, 16);
        s += __shfl_down(s, 2, 16); s += __shfl_down(s, 1, 16);
        float m = __shfl(s, 0, 16) * (1.f / ND);
        float d0 = v0 - m, d1 = v1 - m, d2 = v2 - m;
        float q = d0 * d0 + d1 * d1 + d2 * d2;
        q += __shfl_down(q, 8, 16); q += __shfl_down(q, 4, 16);
        q += __shfl_down(q, 2, 16); q += __shfl_down(q, 1, 16);
        if (i == 0) { mrs[r][0] = m; mrs[r][1] = rsqrtf(q * (1.f / ND) + 1e-5f); }
    }
    __syncthreads();
    if (t < TR * ND) {
        int r = t / ND, c = t % ND;
        hh[r][c] = (nrow[r][c] - mrs[r][0]) * mrs[r][1] * g2v[c] + b2v[c];
    }
    __syncthreads();
    if (t < 384) {
        int col = t % 192, rg = t / 192;
        float w[ND];
        #pragma unroll
        for (int c = 0; c < ND; c++) w[c] = w1[c * 192 + col];
        float bias = fb1[col];
        for (int r = rg * 4; r < rg * 4 + 4; r++) {
            float a = bias;
            #pragma unroll
            for (int c = 0; c < ND; c++) a += hh[r][c] * w[c];
            hid[r * 192 + col] = 0.5f * a * (1.f + erff(a * 0.70710678f));
        }
    }
    __syncthreads();
    if (t < 384) {
        int col = t % ND, kc = (t / ND) & 3, rh = t / 192;
        float w[ND];
        #pragma unroll
        for (int i2 = 0; i2 < ND; i2++) w[i2] = w2[(kc * ND + i2) * ND + col];
        for (int r = rh * 4; r < rh * 4 + 4; r++) {
            float a = 0;
            #pragma unroll
            for (int i2 = 0; i2 < ND; i2++) a += hid[r * 192 + kc * ND + i2] * w[i2];
            part[kc][r][col] = a;
        }
    }
    __syncthreads();
    for (int i = t; i < TR * ND; i += 512) {
        int r = i / ND, c = i % ND;
        int n = n0 + r;
        if (n < NSEQ) {
            fused[((size_t)b * NSEQ + n) * ND + c] =
                nrow[r][c] + fb2[c] + part[0][r][c] + part[1][r][c] + part[2][r][c] + part[3][r][c];
        }
    }
}

__global__ void k_head(const float* __restrict__ fused, const float* __restrict__ lg,
                       const float* __restrict__ lb, const float* __restrict__ cw,
                       const float* __restrict__ cb, float* __restrict__ out) {
    int b = blockIdx.x, t = threadIdx.x;
    __shared__ float part[4][ND];
    __shared__ float gg[ND], mv[2];
    if (t < 192) {
        int col = t % ND, qt = t / ND;
        int nA = qt * 63;
        int nB = (nA + 63 < NSEQ) ? nA + 63 : NSEQ;
        float s = 0.f;
        for (int n = nA; n < nB; n++) s += fused[((size_t)b * NSEQ + n) * ND + col];
        part[qt][col] = s;
    }
    __syncthreads();
    if (t < ND) gg[t] = (part[0][t] + part[1][t] + part[2][t] + part[3][t]) * (1.f / NSEQ);
    __syncthreads();
    if (t == 0) {
        float m = 0;
        for (int c = 0; c < ND; c++) m += gg[c];
        m /= (float)ND;
        float v = 0;
        for (int c = 0; c < ND; c++) { float dd = gg[c] - m; v += dd * dd; }
        v /= (float)ND;
        mv[0] = m; mv[1] = rsqrtf(v + 1e-5f);
    }
    __syncthreads();
    if (t < ND) gg[t] = (gg[t] - mv[0]) * mv[1] * lg[t] + lb[t];
    __syncthreads();
    if (t < 4) {
        float a = cb[t];
        for (int c = 0; c < ND; c++) a += gg[c] * cw[c * 4 + t];
        out[b * 4 + t] = a;
    }
}

extern "C" void kernel_launch(void* const* d_in, const int* in_sizes, int n_in,
                              void* d_out, int out_size, void* d_ws, size_t ws_size,
                              hipStream_t stream) {
    const float* x       = (const float*)d_in[0];
    const float* riem_w1 = (const float*)d_in[1];
    const float* riem_b1 = (const float*)d_in[2];
    const float* riem_w2 = (const float*)d_in[3];
    const float* riem_b2 = (const float*)d_in[4];
    const float* conv1_w = (const float*)d_in[5];
    const float* dw1_w   = (const float*)d_in[6];
    const float* dw2_w   = (const float*)d_in[7];
    const float* pw_w    = (const float*)d_in[8];
    const float* tc1_w   = (const float*)d_in[9];
    const float* tc1_b   = (const float*)d_in[10];
    const float* tc2_w   = (const float*)d_in[11];
    const float* tc2_b   = (const float*)d_in[12];
    const float* fusion  = (const float*)d_in[13];
    const float* pos_enc = (const float*)d_in[14];
    const float* ln1_g   = (const float*)d_in[15];
    const float* ln1_b   = (const float*)d_in[16];
    const float* qkv_w   = (const float*)d_in[17];
    const float* qkv_b   = (const float*)d_in[18];
    const float* apw     = (const float*)d_in[19];
    const float* apb     = (const float*)d_in[20];
    const float* ln2_g   = (const float*)d_in[21];
    const float* ln2_b   = (const float*)d_in[22];
    const float* ffn_w1  = (const float*)d_in[23];
    const float* ffn_b1  = (const float*)d_in[24];
    const float* ffn_w2  = (const float*)d_in[25];
    const float* ffn_b2  = (const float*)d_in[26];
    const float* cls_g   = (const float*)d_in[27];
    const float* cls_b_  = (const float*)d_in[28];
    const float* cls_w   = (const float*)d_in[29];
    const float* cls_bb  = (const float*)d_in[30];
    float* out = (float*)d_out;

    float* ws = (float*)d_ws;
    float* covS  = ws;                 // 4048
    float* sums  = ws + 4048;          // 352
    float* rfeat = ws + 4400;          // 768
    float* feat  = ws + 5168;          // 192000
    float* fused = ws + 197168;        // 192768
    float* pbuf  = ws + 389936;        // 1024000
    __hip_bfloat16* ybuf = (__hip_bfloat16*)(ws + 1413936); // 8192000 bf16

    hipMemsetAsync(covS, 0, 4400 * sizeof(float), stream);

    k_ycov<<<1012, 256, 0, stream>>>(x, dw1_w, ybuf, covS, sums);
    k_convchol<<<4112, 256, 0, stream>>>(ybuf, conv1_w, pbuf, covS, sums,
                                         riem_w1, riem_b1, riem_w2, riem_b2, rfeat);
    k_stage2<<<dim3(63, NB), 256, 0, stream>>>(pbuf, dw2_w, pw_w, feat);
    k_fuse<<<dim3(63, NB), 256, 0, stream>>>(feat, rfeat, tc1_w, tc1_b, tc2_w, tc2_b,
                                             fusion, pos_enc, fused);

    for (int i = 0; i < 4; i++) {
        k_layer<<<dim3(32, NB), 512, 0, stream>>>(
            fused, ln1_g + i * 48, ln1_b + i * 48, qkv_w + i * 6912, qkv_b + i * 144,
            apw + i * 2304, apb + i * 48, ln2_g + i * 48, ln2_b + i * 48,
            ffn_w1 + i * 9216, ffn_b1 + i * 192, ffn_w2 + i * 9216, ffn_b2 + i * 48);
    }

    k_head<<<NB, 256, 0, stream>>>(fused, cls_g, cls_b_, cls_w, cls_bb, out);
}